// Round 7
// baseline (360.079 us; speedup 1.0000x reference)
//
#include <hip/hip_runtime.h>
#include <hip/hip_bf16.h>

// Embedded-Gaussian non-local block, MI355X (gfx950).
// B=8, C=256, E=128, N=64*64=4096. fp32 in/out, bf16 MFMA internally.
//
// Round 7: r5 skeleton (2 barriers/iter, stage-then-compute, 1024 blocks =
// 8b x 32qt x 4sl, 4 waves x 32q) with ONE change: V is NOT staged in LDS.
// vb fragments are q-independent (all 4 waves read the same 16KB V tile ->
// L1-resident; V per batch is 1MB, L2-pinned via b=blk&7 XCD swizzle), so PV
// reads V directly from global. LDS = K(17.4K) + P(19.5K) = 36,864B ->
// 4 blocks/CU (16 waves/CU, launch_bounds(256,4)), doubling occupancy vs r5.
// Softmax: fixed shift p=exp(s-15) (exact by shift invariance); kv-slice
// partials combine by plain addition.

typedef __attribute__((ext_vector_type(8))) short s16x8;
typedef __attribute__((ext_vector_type(4))) short s16x4;
typedef __attribute__((ext_vector_type(4))) float f32x4;

#define B_ 8
#define C_ 256
#define E_ 128
#define N_ 4096
#define SLICES 4
#define SLICE_KV (N_ / SLICES)          // 1024
#define NTILES (SLICE_KV / 64)          // 16 kv tiles per block
#define PST 76                          // P row stride in u16 (write-conflict-free)
#define SHIFT 15.0f

static __device__ __forceinline__ unsigned short f2bf(float f) {
    union { float f; unsigned int u; } v; v.f = f;
    return (unsigned short)((v.u + 0x7FFFu + ((v.u >> 16) & 1u)) >> 16);
}
static __device__ __forceinline__ float bf2f(unsigned short h) {
    union { unsigned int u; float f; } v; v.u = ((unsigned int)h) << 16;
    return v.f;
}

// ---------------------------------------------------------------------------
// Weight pre-conversion: wq/wk/wv [E,C] and wo [C,E] f32 -> bf16.
// ---------------------------------------------------------------------------
__global__ __launch_bounds__(256) void convert_w(
    const float* __restrict__ wq, const float* __restrict__ wk,
    const float* __restrict__ wv, const float* __restrict__ wo,
    unsigned short* __restrict__ wqb, unsigned short* __restrict__ wkb,
    unsigned short* __restrict__ wvb, unsigned short* __restrict__ wob)
{
    const int i = blockIdx.x * 256 + threadIdx.x;   // 0..32767
    wqb[i] = f2bf(wq[i]);
    wkb[i] = f2bf(wk[i]);
    wvb[i] = f2bf(wv[i]);
    wob[i] = f2bf(wo[i]);
}

// ---------------------------------------------------------------------------
// QKV projection (working; bf16 weight A-frags direct loads).
// ---------------------------------------------------------------------------
__global__ __launch_bounds__(256, 2) void qkv_kernel(
    const float* __restrict__ x,
    const unsigned short* __restrict__ wqb, const float* __restrict__ bq,
    const unsigned short* __restrict__ wkb, const float* __restrict__ bk,
    const unsigned short* __restrict__ wvb, const float* __restrict__ bv,
    unsigned short* __restrict__ Q, unsigned short* __restrict__ K,
    unsigned short* __restrict__ Vt)
{
    __shared__ unsigned short xs[64 * 264];   // [n][c], pad 8

    const int tid = threadIdx.x;
    const int b  = blockIdx.x >> 6;
    const int n0 = (blockIdx.x & 63) << 6;

    {
        const int n  = tid & 63;
        const int c0 = tid >> 6;   // 0..3
        const float* xp = x + ((size_t)(b * C_) << 12) + n0 + n;
        for (int it = 0; it < 64; ++it) {
            const int c = it * 4 + c0;
            xs[n * 264 + c] = f2bf(xp[(size_t)c << 12]);
        }
    }
    __syncthreads();

    const int w = tid >> 6, l = tid & 63, hi = l >> 4, lx = l & 15;

    for (int idx = w; idx < 24; idx += 4) {
        const int out = idx >> 3;        // 0=q 1=k 2=v
        const int et  = idx & 7;
        const int e0  = et << 4;
        const unsigned short* W = (out == 0) ? wqb : (out == 1) ? wkb : wvb;
        const float* bias = (out == 0) ? bq : (out == 1) ? bk : bv;

        s16x8 af[8];
        const unsigned short* wp = W + (e0 + lx) * C_ + hi * 8;
#pragma unroll
        for (int ks = 0; ks < 8; ++ks) af[ks] = *(const s16x8*)(wp + ks * 32);

        float bi[4];
#pragma unroll
        for (int r = 0; r < 4; ++r) bi[r] = bias[e0 + hi * 4 + r];

#pragma unroll
        for (int nt = 0; nt < 4; ++nt) {
            f32x4 acc = {0.f, 0.f, 0.f, 0.f};
#pragma unroll
            for (int ks = 0; ks < 8; ++ks) {
                s16x8 xb = *(const s16x8*)&xs[(nt * 16 + lx) * 264 + ks * 32 + hi * 8];
                acc = __builtin_amdgcn_mfma_f32_16x16x32_bf16(af[ks], xb, acc, 0, 0, 0);
            }
            const int n = n0 + nt * 16 + lx;
            if (out < 2) {
                unsigned short* dst =
                    ((out == 0) ? Q : K) + ((size_t)(b * N_ + n) << 7) + e0 + hi * 4;
                s16x4 pk;
#pragma unroll
                for (int r = 0; r < 4; ++r) pk[r] = (short)f2bf(acc[r] + bi[r]);
                *(s16x4*)dst = pk;
            } else {
#pragma unroll
                for (int r = 0; r < 4; ++r)
                    Vt[((size_t)(b * E_ + e0 + hi * 4 + r) << 12) + n] =
                        f2bf(acc[r] + bi[r]);
            }
        }
    }
}

// ---------------------------------------------------------------------------
// Attention partial. 1024 blocks: b = blk&7 (XCD pin), idx = blk>>3:
// sl = idx>>5 (kv slice 0..3), qt = idx&31 (q-tile of 128).
// Wave w: q rows qt*128 + w*32. V read directly from global (L1/L2-resident).
// LDS 36,864B -> 4 blocks/CU; launch_bounds(256,4) caps VGPR at 128.
// ---------------------------------------------------------------------------
__global__ __launch_bounds__(256, 4) void attn_partial(
    const unsigned short* __restrict__ Q, const unsigned short* __restrict__ K,
    const unsigned short* __restrict__ Vt,
    unsigned short* __restrict__ featP, float* __restrict__ denomP)
{
    __shared__ unsigned short Kx[64 * 136];      // [kv][e], stride 272B
    __shared__ unsigned short Ps[4][32 * PST];   // per-wave [q][kv], stride 152B

    const int tid = threadIdx.x;
    const int b   = blockIdx.x & 7;
    const int idx = blockIdx.x >> 3;
    const int sl  = idx >> 5;      // kv slice 0..3
    const int qt  = idx & 31;      // q tile (128 rows)
    const int w = tid >> 6, l = tid & 63, hi = l >> 4, lx = l & 15;
    const int q0 = qt * 128 + w * 32;

    // hoisted Q fragments: 2 subtiles x 4 ks
    s16x8 qA[2][4];
#pragma unroll
    for (int qf = 0; qf < 2; ++qf) {
        const unsigned short* qp =
            Q + ((size_t)(b * N_ + q0 + qf * 16 + lx) << 7) + hi * 8;
#pragma unroll
        for (int ks = 0; ks < 4; ++ks) qA[qf][ks] = *(const s16x8*)(qp + ks * 32);
    }

    f32x4 feat[2][8];
#pragma unroll
    for (int qf = 0; qf < 2; ++qf)
#pragma unroll
        for (int ef = 0; ef < 8; ++ef) feat[qf][ef] = (f32x4){0.f, 0.f, 0.f, 0.f};
    float dAcc[8];
#pragma unroll
    for (int i = 0; i < 8; ++i) dAcc[i] = 0.f;

    const unsigned short* Kg = K + ((size_t)(b * N_) << 7);
    const unsigned short* Vg = Vt + ((size_t)(b * E_) << 12);
    unsigned short* pw = &Ps[w][0];

    for (int it = 0; it < NTILES; ++it) {
        const int kv0 = sl * SLICE_KV + it * 64;
        __syncthreads();   // all waves' kb (and own pa) reads of prev tile done
        // stage K tile [64kv][128e]: lane-contiguous 16B, 256B/instr coalesced
#pragma unroll
        for (int i = 0; i < 4; ++i) {
            const int flat = tid + i * 256;           // 16B units
            const int row = flat >> 4, c16 = flat & 15;
            *(s16x8*)&Kx[row * 136 + c16 * 8] =
                *(const s16x8*)(Kg + (size_t)(kv0 + row) * 128 + c16 * 8);
        }
        __syncthreads();

        // QK^T + exp + P->LDS (per-wave slice, no extra barrier needed)
#pragma unroll
        for (int kvf = 0; kvf < 4; ++kvf) {
            f32x4 s0 = {0.f, 0.f, 0.f, 0.f}, s1 = {0.f, 0.f, 0.f, 0.f};
#pragma unroll
            for (int ks = 0; ks < 4; ++ks) {
                s16x8 kb = *(const s16x8*)&Kx[(kvf * 16 + lx) * 136 + ks * 32 + hi * 8];
                s0 = __builtin_amdgcn_mfma_f32_16x16x32_bf16(qA[0][ks], kb, s0, 0, 0, 0);
                s1 = __builtin_amdgcn_mfma_f32_16x16x32_bf16(qA[1][ks], kb, s1, 0, 0, 0);
            }
#pragma unroll
            for (int r = 0; r < 4; ++r) {
                float p0 = __expf(s0[r] - SHIFT);
                float p1 = __expf(s1[r] - SHIFT);
                dAcc[r]     += p0;
                dAcc[4 + r] += p1;
                pw[(hi * 4 + r) * PST      + kvf * 16 + lx] = f2bf(p0);
                pw[(16 + hi * 4 + r) * PST + kvf * 16 + lx] = f2bf(p1);
            }
        }
        // PV: feat[32q x 128e] += P @ V ; V fragments direct from global
#pragma unroll
        for (int ks = 0; ks < 2; ++ks) {
            s16x8 pa0 = *(const s16x8*)&pw[(lx)      * PST + ks * 32 + hi * 8];
            s16x8 pa1 = *(const s16x8*)&pw[(16 + lx) * PST + ks * 32 + hi * 8];
#pragma unroll
            for (int ef = 0; ef < 8; ++ef) {
                s16x8 vb = *(const s16x8*)(Vg + ((size_t)(ef * 16 + lx) << 12)
                                              + kv0 + ks * 32 + hi * 8);
                feat[0][ef] = __builtin_amdgcn_mfma_f32_16x16x32_bf16(pa0, vb, feat[0][ef], 0, 0, 0);
                feat[1][ef] = __builtin_amdgcn_mfma_f32_16x16x32_bf16(pa1, vb, feat[1][ef], 0, 0, 0);
            }
        }
    }

    // denom: reduce over kv lanes (lx)
#pragma unroll
    for (int i = 0; i < 8; ++i) {
        float v = dAcc[i];
        v += __shfl_xor(v, 1); v += __shfl_xor(v, 2);
        v += __shfl_xor(v, 4); v += __shfl_xor(v, 8);
        dAcc[i] = v;
    }
    const size_t qg = (size_t)((sl * 8 + b) * N_ + q0);
    if (lx == 0) {
        float* dP = denomP + qg;
#pragma unroll
        for (int qf = 0; qf < 2; ++qf)
#pragma unroll
            for (int r = 0; r < 4; ++r)
                dP[qf * 16 + hi * 4 + r] = dAcc[qf * 4 + r];
    }
    unsigned short* fP = featP + (qg << 7);
#pragma unroll
    for (int qf = 0; qf < 2; ++qf)
#pragma unroll
        for (int ef = 0; ef < 8; ++ef)
#pragma unroll
            for (int r = 0; r < 4; ++r)
                fP[(qf * 16 + hi * 4 + r) * 128 + ef * 16 + lx] =
                    f2bf(feat[qf][ef][r]);
}

// ---------------------------------------------------------------------------
// Combine: sum 4 kv-slice partials, normalize, out-proj (swapped operands ->
// n-coalesced stores; B-frags direct s16x8 from wob) + bias + residual.
// grid: 8 b x 64 n-tiles of 64.
// ---------------------------------------------------------------------------
__global__ __launch_bounds__(256, 2) void combine_kernel(
    const unsigned short* __restrict__ featP, const float* __restrict__ denomP,
    const unsigned short* __restrict__ wob, const float* __restrict__ bo,
    const float* __restrict__ x, float* __restrict__ out)
{
    __shared__ unsigned short fs[64 * 136];   // [q][e], stride 272B

    const int tid = threadIdx.x;
    const int b  = blockIdx.x & 7;
    const int nt = blockIdx.x >> 3;          // 0..63

    // sum partials + normalize -> fs (bf16)
    {
        const int q = tid >> 2, eb = (tid & 3) * 32;
        const int n = nt * 64 + q;
        float den = 0.f;
#pragma unroll
        for (int s = 0; s < SLICES; ++s)
            den += denomP[(size_t)((s * 8 + b) * N_) + n];
        const float inv = 1.f / den;
#pragma unroll
        for (int e8 = 0; e8 < 4; ++e8) {
            float acc[8];
#pragma unroll
            for (int j = 0; j < 8; ++j) acc[j] = 0.f;
#pragma unroll
            for (int s = 0; s < SLICES; ++s) {
                s16x8 v = *(const s16x8*)(featP +
                    (((size_t)((s * 8 + b) * N_) + n) << 7) + eb + e8 * 8);
#pragma unroll
                for (int j = 0; j < 8; ++j) acc[j] += bf2f((unsigned short)v[j]);
            }
            s16x8 o;
#pragma unroll
            for (int j = 0; j < 8; ++j) o[j] = (short)f2bf(acc[j] * inv);
            *(s16x8*)&fs[q * 136 + eb + e8 * 8] = o;
        }
    }
    __syncthreads();

    const int w = tid >> 6, l = tid & 63, hi = l >> 4, lx = l & 15;

    // B-frags of feat (col = q)
    s16x8 fa[4];
#pragma unroll
    for (int ks = 0; ks < 4; ++ks)
        fa[ks] = *(const s16x8*)&fs[(w * 16 + lx) * 136 + ks * 32 + hi * 8];

    const int n = nt * 64 + w * 16 + lx;
    const float* xb = x + ((size_t)(b * C_) << 12);
    float* ob = out + ((size_t)(b * C_) << 12);
#pragma unroll 1
    for (int ct = 0; ct < 16; ++ct) {
        const unsigned short* wp = wob + (ct * 16 + lx) * 128 + hi * 8;
        f32x4 acc = {0.f, 0.f, 0.f, 0.f};
#pragma unroll
        for (int ks = 0; ks < 4; ++ks) {
            s16x8 wb = *(const s16x8*)(wp + ks * 32);
            // swapped: D[row=c][col=n]
            acc = __builtin_amdgcn_mfma_f32_16x16x32_bf16(wb, fa[ks], acc, 0, 0, 0);
        }
#pragma unroll
        for (int r = 0; r < 4; ++r) {
            const int c = ct * 16 + hi * 4 + r;
            const size_t off = ((size_t)c << 12) + n;
            ob[off] = acc[r] + bo[c] + xb[off];
        }
    }
}

extern "C" void kernel_launch(void* const* d_in, const int* in_sizes, int n_in,
                              void* d_out, int out_size, void* d_ws, size_t ws_size,
                              hipStream_t stream) {
    (void)in_sizes; (void)n_in; (void)out_size; (void)ws_size;
    const float* x  = (const float*)d_in[0];
    const float* wq = (const float*)d_in[1];
    const float* bq = (const float*)d_in[2];
    const float* wk = (const float*)d_in[3];
    const float* bk = (const float*)d_in[4];
    const float* wv = (const float*)d_in[5];
    const float* bv = (const float*)d_in[6];
    const float* wo = (const float*)d_in[7];
    const float* bo = (const float*)d_in[8];

    unsigned short* Q  = (unsigned short*)d_ws;                 // [B,N,E] bf16
    unsigned short* K  = Q + (size_t)B_ * N_ * E_;
    unsigned short* Vt = K + (size_t)B_ * N_ * E_;              // [B,E,N] bf16
    unsigned short* featP = Vt + (size_t)B_ * N_ * E_;          // [SLICES][B][N][E] bf16
    float* denomP = (float*)(featP + (size_t)SLICES * B_ * N_ * E_); // [SLICES][B][N]
    unsigned short* wqb = (unsigned short*)(denomP + (size_t)SLICES * B_ * N_);
    unsigned short* wkb = wqb + E_ * C_;
    unsigned short* wvb = wkb + E_ * C_;
    unsigned short* wob = wvb + E_ * C_;                        // [C,E] bf16

    convert_w<<<dim3(128), dim3(256), 0, stream>>>(
        wq, wk, wv, wo, wqb, wkb, wvb, wob);
    qkv_kernel<<<dim3(B_ * (N_ / 64)), dim3(256), 0, stream>>>(
        x, wqb, bq, wkb, bk, wvb, bv, Q, K, Vt);
    attn_partial<<<dim3(B_ * 32 * SLICES), dim3(256), 0, stream>>>(
        Q, K, Vt, featP, denomP);
    combine_kernel<<<dim3(B_ * 64), dim3(256), 0, stream>>>(
        featP, denomP, wob, bo, x, (float*)d_out);
}

// Round 8
// 204.098 us; speedup vs baseline: 1.7642x; 1.7642x over previous
//
#include <hip/hip_runtime.h>
#include <hip/hip_bf16.h>

// Embedded-Gaussian non-local block, MI355X (gfx950).
// B=8, C=256, E=128, N=64*64=4096. fp32 in/out, bf16 MFMA internally.
//
// Round 8 = round 7 with attn launch_bounds reverted (256,4)->(256,2).
// Lesson (r3/r4/r7): hard waves/EU targets >2 make the allocator spill the
// 64-reg feat accumulator (r7: VGPR 64, 1.1GB spill traffic). Natural
// allocation under (256,2) is ~112 regs -> 4 waves/SIMD permitted; with V
// un-staged LDS = K(17.4K)+P(19.5K) = 36,864B -> 4 blocks/CU. Occupancy
// comes from relaxed regalloc + small LDS, not from the bound.
// V fragments are q-independent and read straight from global (L1/L2;
// V per batch = 1MB, L2-pinned via b=blk&7 XCD swizzle).
// Softmax: fixed shift p=exp(s-15) (exact by shift invariance); kv-slice
// partials combine by plain addition.

typedef __attribute__((ext_vector_type(8))) short s16x8;
typedef __attribute__((ext_vector_type(4))) short s16x4;
typedef __attribute__((ext_vector_type(4))) float f32x4;

#define B_ 8
#define C_ 256
#define E_ 128
#define N_ 4096
#define SLICES 4
#define SLICE_KV (N_ / SLICES)          // 1024
#define NTILES (SLICE_KV / 64)          // 16 kv tiles per block
#define PST 76                          // P row stride in u16 (write-conflict-free)
#define SHIFT 15.0f

static __device__ __forceinline__ unsigned short f2bf(float f) {
    union { float f; unsigned int u; } v; v.f = f;
    return (unsigned short)((v.u + 0x7FFFu + ((v.u >> 16) & 1u)) >> 16);
}
static __device__ __forceinline__ float bf2f(unsigned short h) {
    union { unsigned int u; float f; } v; v.u = ((unsigned int)h) << 16;
    return v.f;
}

// ---------------------------------------------------------------------------
// Weight pre-conversion: wq/wk/wv [E,C] and wo [C,E] f32 -> bf16.
// ---------------------------------------------------------------------------
__global__ __launch_bounds__(256) void convert_w(
    const float* __restrict__ wq, const float* __restrict__ wk,
    const float* __restrict__ wv, const float* __restrict__ wo,
    unsigned short* __restrict__ wqb, unsigned short* __restrict__ wkb,
    unsigned short* __restrict__ wvb, unsigned short* __restrict__ wob)
{
    const int i = blockIdx.x * 256 + threadIdx.x;   // 0..32767
    wqb[i] = f2bf(wq[i]);
    wkb[i] = f2bf(wk[i]);
    wvb[i] = f2bf(wv[i]);
    wob[i] = f2bf(wo[i]);
}

// ---------------------------------------------------------------------------
// QKV projection (working; bf16 weight A-frags direct loads).
// ---------------------------------------------------------------------------
__global__ __launch_bounds__(256, 2) void qkv_kernel(
    const float* __restrict__ x,
    const unsigned short* __restrict__ wqb, const float* __restrict__ bq,
    const unsigned short* __restrict__ wkb, const float* __restrict__ bk,
    const unsigned short* __restrict__ wvb, const float* __restrict__ bv,
    unsigned short* __restrict__ Q, unsigned short* __restrict__ K,
    unsigned short* __restrict__ Vt)
{
    __shared__ unsigned short xs[64 * 264];   // [n][c], pad 8

    const int tid = threadIdx.x;
    const int b  = blockIdx.x >> 6;
    const int n0 = (blockIdx.x & 63) << 6;

    {
        const int n  = tid & 63;
        const int c0 = tid >> 6;   // 0..3
        const float* xp = x + ((size_t)(b * C_) << 12) + n0 + n;
        for (int it = 0; it < 64; ++it) {
            const int c = it * 4 + c0;
            xs[n * 264 + c] = f2bf(xp[(size_t)c << 12]);
        }
    }
    __syncthreads();

    const int w = tid >> 6, l = tid & 63, hi = l >> 4, lx = l & 15;

    for (int idx = w; idx < 24; idx += 4) {
        const int out = idx >> 3;        // 0=q 1=k 2=v
        const int et  = idx & 7;
        const int e0  = et << 4;
        const unsigned short* W = (out == 0) ? wqb : (out == 1) ? wkb : wvb;
        const float* bias = (out == 0) ? bq : (out == 1) ? bk : bv;

        s16x8 af[8];
        const unsigned short* wp = W + (e0 + lx) * C_ + hi * 8;
#pragma unroll
        for (int ks = 0; ks < 8; ++ks) af[ks] = *(const s16x8*)(wp + ks * 32);

        float bi[4];
#pragma unroll
        for (int r = 0; r < 4; ++r) bi[r] = bias[e0 + hi * 4 + r];

#pragma unroll
        for (int nt = 0; nt < 4; ++nt) {
            f32x4 acc = {0.f, 0.f, 0.f, 0.f};
#pragma unroll
            for (int ks = 0; ks < 8; ++ks) {
                s16x8 xb = *(const s16x8*)&xs[(nt * 16 + lx) * 264 + ks * 32 + hi * 8];
                acc = __builtin_amdgcn_mfma_f32_16x16x32_bf16(af[ks], xb, acc, 0, 0, 0);
            }
            const int n = n0 + nt * 16 + lx;
            if (out < 2) {
                unsigned short* dst =
                    ((out == 0) ? Q : K) + ((size_t)(b * N_ + n) << 7) + e0 + hi * 4;
                s16x4 pk;
#pragma unroll
                for (int r = 0; r < 4; ++r) pk[r] = (short)f2bf(acc[r] + bi[r]);
                *(s16x4*)dst = pk;
            } else {
#pragma unroll
                for (int r = 0; r < 4; ++r)
                    Vt[((size_t)(b * E_ + e0 + hi * 4 + r) << 12) + n] =
                        f2bf(acc[r] + bi[r]);
            }
        }
    }
}

// ---------------------------------------------------------------------------
// Attention partial. 1024 blocks: b = blk&7 (XCD pin), idx = blk>>3:
// sl = idx>>5 (kv slice 0..3), qt = idx&31 (q-tile of 128).
// Wave w: q rows qt*128 + w*32. V read directly from global (L1/L2-resident).
// LDS 36,864B; launch_bounds(256,2) = relaxed cap (natural ~112 regs ->
// up to 4 blocks/CU).
// ---------------------------------------------------------------------------
__global__ __launch_bounds__(256, 2) void attn_partial(
    const unsigned short* __restrict__ Q, const unsigned short* __restrict__ K,
    const unsigned short* __restrict__ Vt,
    unsigned short* __restrict__ featP, float* __restrict__ denomP)
{
    __shared__ unsigned short Kx[64 * 136];      // [kv][e], stride 272B
    __shared__ unsigned short Ps[4][32 * PST];   // per-wave [q][kv], stride 152B

    const int tid = threadIdx.x;
    const int b   = blockIdx.x & 7;
    const int idx = blockIdx.x >> 3;
    const int sl  = idx >> 5;      // kv slice 0..3
    const int qt  = idx & 31;      // q tile (128 rows)
    const int w = tid >> 6, l = tid & 63, hi = l >> 4, lx = l & 15;
    const int q0 = qt * 128 + w * 32;

    // hoisted Q fragments: 2 subtiles x 4 ks
    s16x8 qA[2][4];
#pragma unroll
    for (int qf = 0; qf < 2; ++qf) {
        const unsigned short* qp =
            Q + ((size_t)(b * N_ + q0 + qf * 16 + lx) << 7) + hi * 8;
#pragma unroll
        for (int ks = 0; ks < 4; ++ks) qA[qf][ks] = *(const s16x8*)(qp + ks * 32);
    }

    f32x4 feat[2][8];
#pragma unroll
    for (int qf = 0; qf < 2; ++qf)
#pragma unroll
        for (int ef = 0; ef < 8; ++ef) feat[qf][ef] = (f32x4){0.f, 0.f, 0.f, 0.f};
    float dAcc[8];
#pragma unroll
    for (int i = 0; i < 8; ++i) dAcc[i] = 0.f;

    const unsigned short* Kg = K + ((size_t)(b * N_) << 7);
    const unsigned short* Vg = Vt + ((size_t)(b * E_) << 12);
    unsigned short* pw = &Ps[w][0];

    for (int it = 0; it < NTILES; ++it) {
        const int kv0 = sl * SLICE_KV + it * 64;
        __syncthreads();   // all waves' kb reads of prev tile done
        // stage K tile [64kv][128e]: lane-contiguous 16B, 256B/instr coalesced
#pragma unroll
        for (int i = 0; i < 4; ++i) {
            const int flat = tid + i * 256;           // 16B units
            const int row = flat >> 4, c16 = flat & 15;
            *(s16x8*)&Kx[row * 136 + c16 * 8] =
                *(const s16x8*)(Kg + (size_t)(kv0 + row) * 128 + c16 * 8);
        }
        __syncthreads();

        // QK^T + exp + P->LDS (per-wave slice, no extra barrier needed)
#pragma unroll
        for (int kvf = 0; kvf < 4; ++kvf) {
            f32x4 s0 = {0.f, 0.f, 0.f, 0.f}, s1 = {0.f, 0.f, 0.f, 0.f};
#pragma unroll
            for (int ks = 0; ks < 4; ++ks) {
                s16x8 kb = *(const s16x8*)&Kx[(kvf * 16 + lx) * 136 + ks * 32 + hi * 8];
                s0 = __builtin_amdgcn_mfma_f32_16x16x32_bf16(qA[0][ks], kb, s0, 0, 0, 0);
                s1 = __builtin_amdgcn_mfma_f32_16x16x32_bf16(qA[1][ks], kb, s1, 0, 0, 0);
            }
#pragma unroll
            for (int r = 0; r < 4; ++r) {
                float p0 = __expf(s0[r] - SHIFT);
                float p1 = __expf(s1[r] - SHIFT);
                dAcc[r]     += p0;
                dAcc[4 + r] += p1;
                pw[(hi * 4 + r) * PST      + kvf * 16 + lx] = f2bf(p0);
                pw[(16 + hi * 4 + r) * PST + kvf * 16 + lx] = f2bf(p1);
            }
        }
        // PV: feat[32q x 128e] += P @ V ; V fragments direct from global
#pragma unroll
        for (int ks = 0; ks < 2; ++ks) {
            s16x8 pa0 = *(const s16x8*)&pw[(lx)      * PST + ks * 32 + hi * 8];
            s16x8 pa1 = *(const s16x8*)&pw[(16 + lx) * PST + ks * 32 + hi * 8];
#pragma unroll
            for (int ef = 0; ef < 8; ++ef) {
                s16x8 vb = *(const s16x8*)(Vg + ((size_t)(ef * 16 + lx) << 12)
                                              + kv0 + ks * 32 + hi * 8);
                feat[0][ef] = __builtin_amdgcn_mfma_f32_16x16x32_bf16(pa0, vb, feat[0][ef], 0, 0, 0);
                feat[1][ef] = __builtin_amdgcn_mfma_f32_16x16x32_bf16(pa1, vb, feat[1][ef], 0, 0, 0);
            }
        }
    }

    // denom: reduce over kv lanes (lx)
#pragma unroll
    for (int i = 0; i < 8; ++i) {
        float v = dAcc[i];
        v += __shfl_xor(v, 1); v += __shfl_xor(v, 2);
        v += __shfl_xor(v, 4); v += __shfl_xor(v, 8);
        dAcc[i] = v;
    }
    const size_t qg = (size_t)((sl * 8 + b) * N_ + q0);
    if (lx == 0) {
        float* dP = denomP + qg;
#pragma unroll
        for (int qf = 0; qf < 2; ++qf)
#pragma unroll
            for (int r = 0; r < 4; ++r)
                dP[qf * 16 + hi * 4 + r] = dAcc[qf * 4 + r];
    }
    unsigned short* fP = featP + (qg << 7);
#pragma unroll
    for (int qf = 0; qf < 2; ++qf)
#pragma unroll
        for (int ef = 0; ef < 8; ++ef)
#pragma unroll
            for (int r = 0; r < 4; ++r)
                fP[(qf * 16 + hi * 4 + r) * 128 + ef * 16 + lx] =
                    f2bf(feat[qf][ef][r]);
}

// ---------------------------------------------------------------------------
// Combine: sum 4 kv-slice partials, normalize, out-proj (swapped operands ->
// n-coalesced stores; B-frags direct s16x8 from wob) + bias + residual.
// grid: 8 b x 64 n-tiles of 64.
// ---------------------------------------------------------------------------
__global__ __launch_bounds__(256, 2) void combine_kernel(
    const unsigned short* __restrict__ featP, const float* __restrict__ denomP,
    const unsigned short* __restrict__ wob, const float* __restrict__ bo,
    const float* __restrict__ x, float* __restrict__ out)
{
    __shared__ unsigned short fs[64 * 136];   // [q][e], stride 272B

    const int tid = threadIdx.x;
    const int b  = blockIdx.x & 7;
    const int nt = blockIdx.x >> 3;          // 0..63

    // sum partials + normalize -> fs (bf16)
    {
        const int q = tid >> 2, eb = (tid & 3) * 32;
        const int n = nt * 64 + q;
        float den = 0.f;
#pragma unroll
        for (int s = 0; s < SLICES; ++s)
            den += denomP[(size_t)((s * 8 + b) * N_) + n];
        const float inv = 1.f / den;
#pragma unroll
        for (int e8 = 0; e8 < 4; ++e8) {
            float acc[8];
#pragma unroll
            for (int j = 0; j < 8; ++j) acc[j] = 0.f;
#pragma unroll
            for (int s = 0; s < SLICES; ++s) {
                s16x8 v = *(const s16x8*)(featP +
                    (((size_t)((s * 8 + b) * N_) + n) << 7) + eb + e8 * 8);
#pragma unroll
                for (int j = 0; j < 8; ++j) acc[j] += bf2f((unsigned short)v[j]);
            }
            s16x8 o;
#pragma unroll
            for (int j = 0; j < 8; ++j) o[j] = (short)f2bf(acc[j] * inv);
            *(s16x8*)&fs[q * 136 + eb + e8 * 8] = o;
        }
    }
    __syncthreads();

    const int w = tid >> 6, l = tid & 63, hi = l >> 4, lx = l & 15;

    // B-frags of feat (col = q)
    s16x8 fa[4];
#pragma unroll
    for (int ks = 0; ks < 4; ++ks)
        fa[ks] = *(const s16x8*)&fs[(w * 16 + lx) * 136 + ks * 32 + hi * 8];

    const int n = nt * 64 + w * 16 + lx;
    const float* xb = x + ((size_t)(b * C_) << 12);
    float* ob = out + ((size_t)(b * C_) << 12);
#pragma unroll 1
    for (int ct = 0; ct < 16; ++ct) {
        const unsigned short* wp = wob + (ct * 16 + lx) * 128 + hi * 8;
        f32x4 acc = {0.f, 0.f, 0.f, 0.f};
#pragma unroll
        for (int ks = 0; ks < 4; ++ks) {
            s16x8 wb = *(const s16x8*)(wp + ks * 32);
            // swapped: D[row=c][col=n]
            acc = __builtin_amdgcn_mfma_f32_16x16x32_bf16(wb, fa[ks], acc, 0, 0, 0);
        }
#pragma unroll
        for (int r = 0; r < 4; ++r) {
            const int c = ct * 16 + hi * 4 + r;
            const size_t off = ((size_t)c << 12) + n;
            ob[off] = acc[r] + bo[c] + xb[off];
        }
    }
}

extern "C" void kernel_launch(void* const* d_in, const int* in_sizes, int n_in,
                              void* d_out, int out_size, void* d_ws, size_t ws_size,
                              hipStream_t stream) {
    (void)in_sizes; (void)n_in; (void)out_size; (void)ws_size;
    const float* x  = (const float*)d_in[0];
    const float* wq = (const float*)d_in[1];
    const float* bq = (const float*)d_in[2];
    const float* wk = (const float*)d_in[3];
    const float* bk = (const float*)d_in[4];
    const float* wv = (const float*)d_in[5];
    const float* bv = (const float*)d_in[6];
    const float* wo = (const float*)d_in[7];
    const float* bo = (const float*)d_in[8];

    unsigned short* Q  = (unsigned short*)d_ws;                 // [B,N,E] bf16
    unsigned short* K  = Q + (size_t)B_ * N_ * E_;
    unsigned short* Vt = K + (size_t)B_ * N_ * E_;              // [B,E,N] bf16
    unsigned short* featP = Vt + (size_t)B_ * N_ * E_;          // [SLICES][B][N][E] bf16
    float* denomP = (float*)(featP + (size_t)SLICES * B_ * N_ * E_); // [SLICES][B][N]
    unsigned short* wqb = (unsigned short*)(denomP + (size_t)SLICES * B_ * N_);
    unsigned short* wkb = wqb + E_ * C_;
    unsigned short* wvb = wkb + E_ * C_;
    unsigned short* wob = wvb + E_ * C_;                        // [C,E] bf16

    convert_w<<<dim3(128), dim3(256), 0, stream>>>(
        wq, wk, wv, wo, wqb, wkb, wvb, wob);
    qkv_kernel<<<dim3(B_ * (N_ / 64)), dim3(256), 0, stream>>>(
        x, wqb, bq, wkb, bk, wvb, bv, Q, K, Vt);
    attn_partial<<<dim3(B_ * 32 * SLICES), dim3(256), 0, stream>>>(
        Q, K, Vt, featP, denomP);
    combine_kernel<<<dim3(B_ * 64), dim3(256), 0, stream>>>(
        featP, denomP, wob, bo, x, (float*)d_out);
}

// Round 9
// 175.814 us; speedup vs baseline: 2.0481x; 1.1609x over previous
//
#include <hip/hip_runtime.h>
#include <hip/hip_bf16.h>

// Embedded-Gaussian non-local block, MI355X (gfx950).
// B=8, C=256, E=128, N=64*64=4096. fp32 in/out, bf16 MFMA internally.
//
// Round 9 = r5 structure (V staged in LDS, 2 barriers/iter, 1024 blocks =
// 8b x 32qt x 4sl, 4 waves x 32q, relaxed launch_bounds(256,2)) with:
//   - K/V staging via __builtin_amdgcn_global_load_lds width=16 (no VGPR
//     round-trip). LDS is LINEAR [64][128] / [128][64]; the global SOURCE
//     granule is pre-swizzled (c16 ^= row&7) and reads apply the same XOR
//     (rule #21 both-sides swizzle) -> 2-way max on all LDS accesses.
//   - exp2 softmax: Q pre-scaled by log2(e) in qkv, so p = exp2(s' - 15*log2e)
//     (exact same values as exp(s-15); saves a v_mul per element).
// Lessons kept: no waves/EU bound >2 (r3/r4/r7 spill); occupancy is reg-capped
// at 8 waves/CU (VGPR+AGPR ~176) -- win comes from less serialized work/wave.
// Softmax fixed-shift partials combine by plain addition across kv slices.

typedef __attribute__((ext_vector_type(8))) short s16x8;
typedef __attribute__((ext_vector_type(4))) short s16x4;
typedef __attribute__((ext_vector_type(4))) float f32x4;

#define B_ 8
#define C_ 256
#define E_ 128
#define N_ 4096
#define SLICES 4
#define SLICE_KV (N_ / SLICES)          // 1024
#define NTILES (SLICE_KV / 64)          // 16 kv tiles per block
#define PST 76                          // P row stride in u16 (write-conflict-free)
#define LOG2E 1.44269504f
#define SHIFT2 21.6404256f              // 15 * log2(e)

// async global->LDS, 16B per lane; dest = lds base (wave-uniform) + lane*16
#define GLDS16(g, l) __builtin_amdgcn_global_load_lds( \
    (const __attribute__((address_space(1))) void*)(g), \
    (__attribute__((address_space(3))) void*)(l), 16, 0, 0)

static __device__ __forceinline__ unsigned short f2bf(float f) {
    union { float f; unsigned int u; } v; v.f = f;
    return (unsigned short)((v.u + 0x7FFFu + ((v.u >> 16) & 1u)) >> 16);
}
static __device__ __forceinline__ float bf2f(unsigned short h) {
    union { unsigned int u; float f; } v; v.u = ((unsigned int)h) << 16;
    return v.f;
}

// ---------------------------------------------------------------------------
// Weight pre-conversion: wq/wk/wv [E,C] and wo [C,E] f32 -> bf16.
// ---------------------------------------------------------------------------
__global__ __launch_bounds__(256) void convert_w(
    const float* __restrict__ wq, const float* __restrict__ wk,
    const float* __restrict__ wv, const float* __restrict__ wo,
    unsigned short* __restrict__ wqb, unsigned short* __restrict__ wkb,
    unsigned short* __restrict__ wvb, unsigned short* __restrict__ wob)
{
    const int i = blockIdx.x * 256 + threadIdx.x;   // 0..32767
    wqb[i] = f2bf(wq[i]);
    wkb[i] = f2bf(wk[i]);
    wvb[i] = f2bf(wv[i]);
    wob[i] = f2bf(wo[i]);
}

// ---------------------------------------------------------------------------
// QKV projection. Q outputs pre-scaled by log2(e) for the exp2 softmax.
// ---------------------------------------------------------------------------
__global__ __launch_bounds__(256, 2) void qkv_kernel(
    const float* __restrict__ x,
    const unsigned short* __restrict__ wqb, const float* __restrict__ bq,
    const unsigned short* __restrict__ wkb, const float* __restrict__ bk,
    const unsigned short* __restrict__ wvb, const float* __restrict__ bv,
    unsigned short* __restrict__ Q, unsigned short* __restrict__ K,
    unsigned short* __restrict__ Vt)
{
    __shared__ unsigned short xs[64 * 264];   // [n][c], pad 8

    const int tid = threadIdx.x;
    const int b  = blockIdx.x >> 6;
    const int n0 = (blockIdx.x & 63) << 6;

    {
        const int n  = tid & 63;
        const int c0 = tid >> 6;   // 0..3
        const float* xp = x + ((size_t)(b * C_) << 12) + n0 + n;
        for (int it = 0; it < 64; ++it) {
            const int c = it * 4 + c0;
            xs[n * 264 + c] = f2bf(xp[(size_t)c << 12]);
        }
    }
    __syncthreads();

    const int w = tid >> 6, l = tid & 63, hi = l >> 4, lx = l & 15;

    for (int idx = w; idx < 24; idx += 4) {
        const int out = idx >> 3;        // 0=q 1=k 2=v
        const int et  = idx & 7;
        const int e0  = et << 4;
        const unsigned short* W = (out == 0) ? wqb : (out == 1) ? wkb : wvb;
        const float* bias = (out == 0) ? bq : (out == 1) ? bk : bv;
        const float scale = (out == 0) ? LOG2E : 1.0f;

        s16x8 af[8];
        const unsigned short* wp = W + (e0 + lx) * C_ + hi * 8;
#pragma unroll
        for (int ks = 0; ks < 8; ++ks) af[ks] = *(const s16x8*)(wp + ks * 32);

        float bi[4];
#pragma unroll
        for (int r = 0; r < 4; ++r) bi[r] = bias[e0 + hi * 4 + r];

#pragma unroll
        for (int nt = 0; nt < 4; ++nt) {
            f32x4 acc = {0.f, 0.f, 0.f, 0.f};
#pragma unroll
            for (int ks = 0; ks < 8; ++ks) {
                s16x8 xb = *(const s16x8*)&xs[(nt * 16 + lx) * 264 + ks * 32 + hi * 8];
                acc = __builtin_amdgcn_mfma_f32_16x16x32_bf16(af[ks], xb, acc, 0, 0, 0);
            }
            const int n = n0 + nt * 16 + lx;
            if (out < 2) {
                unsigned short* dst =
                    ((out == 0) ? Q : K) + ((size_t)(b * N_ + n) << 7) + e0 + hi * 4;
                s16x4 pk;
#pragma unroll
                for (int r = 0; r < 4; ++r) pk[r] = (short)f2bf((acc[r] + bi[r]) * scale);
                *(s16x4*)dst = pk;
            } else {
#pragma unroll
                for (int r = 0; r < 4; ++r)
                    Vt[((size_t)(b * E_ + e0 + hi * 4 + r) << 12) + n] =
                        f2bf(acc[r] + bi[r]);
            }
        }
    }
}

// ---------------------------------------------------------------------------
// Attention partial. 1024 blocks: b = blk&7 (XCD pin), idx = blk>>3:
// sl = idx>>5 (kv slice 0..3), qt = idx&31 (q-tile of 128).
// Wave w: q rows qt*128 + w*32. K/V staged via global_load_lds (linear LDS,
// source-swizzled); reads XOR the same involution -> <=2-way banks.
// ---------------------------------------------------------------------------
__global__ __launch_bounds__(256, 2) void attn_partial(
    const unsigned short* __restrict__ Q, const unsigned short* __restrict__ K,
    const unsigned short* __restrict__ Vt,
    unsigned short* __restrict__ featP, float* __restrict__ denomP)
{
    __shared__ unsigned short Kx[64 * 128];      // [kv][e], LINEAR, src-swizzled
    __shared__ unsigned short Vs[128 * 64];      // [e][kv], LINEAR, src-swizzled
    __shared__ unsigned short Ps[4][32 * PST];   // per-wave [q][kv], stride 152B

    const int tid = threadIdx.x;
    const int b   = blockIdx.x & 7;
    const int idx = blockIdx.x >> 3;
    const int sl  = idx >> 5;      // kv slice 0..3
    const int qt  = idx & 31;      // q tile (128 rows)
    const int w = tid >> 6, l = tid & 63, hi = l >> 4, lx = l & 15;
    const int q0 = qt * 128 + w * 32;

    // hoisted Q fragments: 2 subtiles x 4 ks
    s16x8 qA[2][4];
#pragma unroll
    for (int qf = 0; qf < 2; ++qf) {
        const unsigned short* qp =
            Q + ((size_t)(b * N_ + q0 + qf * 16 + lx) << 7) + hi * 8;
#pragma unroll
        for (int ks = 0; ks < 4; ++ks) qA[qf][ks] = *(const s16x8*)(qp + ks * 32);
    }

    f32x4 feat[2][8];
#pragma unroll
    for (int qf = 0; qf < 2; ++qf)
#pragma unroll
        for (int ef = 0; ef < 8; ++ef) feat[qf][ef] = (f32x4){0.f, 0.f, 0.f, 0.f};
    float dAcc[8];
#pragma unroll
    for (int i = 0; i < 8; ++i) dAcc[i] = 0.f;

    const unsigned short* Kg = K + ((size_t)(b * N_) << 7);
    const unsigned short* Vg = Vt + ((size_t)(b * E_) << 12);
    unsigned short* pw = &Ps[w][0];

    // staging geometry (fixed per thread): lane's 16B granule
    // K: flat = tid + i*256; row = flat>>4, c16 = flat&15; LDS[row][c16] gets
    //    global granule (c16 ^ (row&7)) of row  -> read XORs the same.
    // V: flat -> e = flat>>3, c8 = flat&7; source granule c8 ^ (e&7).

    for (int it = 0; it < NTILES; ++it) {
        const int kv0 = sl * SLICE_KV + it * 64;
        __syncthreads();   // all waves' reads of prev tile done before overwrite
#pragma unroll
        for (int i = 0; i < 4; ++i) {
            const int flat = tid + i * 256;
            const int row = flat >> 4, c16 = flat & 15;
            GLDS16(Kg + (size_t)(kv0 + row) * 128 + ((c16 ^ (row & 7)) << 3),
                   &Kx[(i * 256 + w * 64) << 3]);
        }
#pragma unroll
        for (int i = 0; i < 4; ++i) {
            const int flat = tid + i * 256;
            const int e = flat >> 3, c8 = flat & 7;
            GLDS16(Vg + (((size_t)e << 12) + kv0) + ((c8 ^ (e & 7)) << 3),
                   &Vs[(i * 256 + w * 64) << 3]);
        }
        __syncthreads();   // vmcnt(0) drained here -> K/V tile visible

        // QK^T + exp2 + P->LDS (per-wave slice)
#pragma unroll
        for (int kvf = 0; kvf < 4; ++kvf) {
            f32x4 s0 = {0.f, 0.f, 0.f, 0.f}, s1 = {0.f, 0.f, 0.f, 0.f};
#pragma unroll
            for (int ks = 0; ks < 4; ++ks) {
                s16x8 kb = *(const s16x8*)&Kx[((kvf * 16 + lx) << 7) +
                                              (((ks * 4 + hi) ^ (lx & 7)) << 3)];
                s0 = __builtin_amdgcn_mfma_f32_16x16x32_bf16(qA[0][ks], kb, s0, 0, 0, 0);
                s1 = __builtin_amdgcn_mfma_f32_16x16x32_bf16(qA[1][ks], kb, s1, 0, 0, 0);
            }
#pragma unroll
            for (int r = 0; r < 4; ++r) {
                float p0 = __builtin_exp2f(s0[r] - SHIFT2);
                float p1 = __builtin_exp2f(s1[r] - SHIFT2);
                dAcc[r]     += p0;
                dAcc[4 + r] += p1;
                pw[(hi * 4 + r) * PST      + kvf * 16 + lx] = f2bf(p0);
                pw[(16 + hi * 4 + r) * PST + kvf * 16 + lx] = f2bf(p1);
            }
        }
        // PV: feat[32q x 128e] += P @ V (P wave-private: no barrier needed)
#pragma unroll
        for (int ks = 0; ks < 2; ++ks) {
            s16x8 pa0 = *(const s16x8*)&pw[(lx)      * PST + ks * 32 + hi * 8];
            s16x8 pa1 = *(const s16x8*)&pw[(16 + lx) * PST + ks * 32 + hi * 8];
#pragma unroll
            for (int ef = 0; ef < 8; ++ef) {
                s16x8 vb = *(const s16x8*)&Vs[((ef * 16 + lx) << 6) +
                                              (((ks * 4 + hi) ^ (lx & 7)) << 3)];
                feat[0][ef] = __builtin_amdgcn_mfma_f32_16x16x32_bf16(pa0, vb, feat[0][ef], 0, 0, 0);
                feat[1][ef] = __builtin_amdgcn_mfma_f32_16x16x32_bf16(pa1, vb, feat[1][ef], 0, 0, 0);
            }
        }
    }

    // denom: reduce over kv lanes (lx)
#pragma unroll
    for (int i = 0; i < 8; ++i) {
        float v = dAcc[i];
        v += __shfl_xor(v, 1); v += __shfl_xor(v, 2);
        v += __shfl_xor(v, 4); v += __shfl_xor(v, 8);
        dAcc[i] = v;
    }
    const size_t qg = (size_t)((sl * 8 + b) * N_ + q0);
    if (lx == 0) {
        float* dP = denomP + qg;
#pragma unroll
        for (int qf = 0; qf < 2; ++qf)
#pragma unroll
            for (int r = 0; r < 4; ++r)
                dP[qf * 16 + hi * 4 + r] = dAcc[qf * 4 + r];
    }
    unsigned short* fP = featP + (qg << 7);
#pragma unroll
    for (int qf = 0; qf < 2; ++qf)
#pragma unroll
        for (int ef = 0; ef < 8; ++ef)
#pragma unroll
            for (int r = 0; r < 4; ++r)
                fP[(qf * 16 + hi * 4 + r) * 128 + ef * 16 + lx] =
                    f2bf(feat[qf][ef][r]);
}

// ---------------------------------------------------------------------------
// Combine: sum 4 kv-slice partials, normalize, out-proj (swapped operands ->
// n-coalesced stores; B-frags direct s16x8 from wob) + bias + residual.
// grid: 8 b x 64 n-tiles of 64.
// ---------------------------------------------------------------------------
__global__ __launch_bounds__(256, 2) void combine_kernel(
    const unsigned short* __restrict__ featP, const float* __restrict__ denomP,
    const unsigned short* __restrict__ wob, const float* __restrict__ bo,
    const float* __restrict__ x, float* __restrict__ out)
{
    __shared__ unsigned short fs[64 * 136];   // [q][e], stride 272B

    const int tid = threadIdx.x;
    const int b  = blockIdx.x & 7;
    const int nt = blockIdx.x >> 3;          // 0..63

    // sum partials + normalize -> fs (bf16)
    {
        const int q = tid >> 2, eb = (tid & 3) * 32;
        const int n = nt * 64 + q;
        float den = 0.f;
#pragma unroll
        for (int s = 0; s < SLICES; ++s)
            den += denomP[(size_t)((s * 8 + b) * N_) + n];
        const float inv = 1.f / den;
#pragma unroll
        for (int e8 = 0; e8 < 4; ++e8) {
            float acc[8];
#pragma unroll
            for (int j = 0; j < 8; ++j) acc[j] = 0.f;
#pragma unroll
            for (int s = 0; s < SLICES; ++s) {
                s16x8 v = *(const s16x8*)(featP +
                    (((size_t)((s * 8 + b) * N_) + n) << 7) + eb + e8 * 8);
#pragma unroll
                for (int j = 0; j < 8; ++j) acc[j] += bf2f((unsigned short)v[j]);
            }
            s16x8 o;
#pragma unroll
            for (int j = 0; j < 8; ++j) o[j] = (short)f2bf(acc[j] * inv);
            *(s16x8*)&fs[q * 136 + eb + e8 * 8] = o;
        }
    }
    __syncthreads();

    const int w = tid >> 6, l = tid & 63, hi = l >> 4, lx = l & 15;

    // B-frags of feat (col = q)
    s16x8 fa[4];
#pragma unroll
    for (int ks = 0; ks < 4; ++ks)
        fa[ks] = *(const s16x8*)&fs[(w * 16 + lx) * 136 + ks * 32 + hi * 8];

    const int n = nt * 64 + w * 16 + lx;
    const float* xb = x + ((size_t)(b * C_) << 12);
    float* ob = out + ((size_t)(b * C_) << 12);
#pragma unroll 1
    for (int ct = 0; ct < 16; ++ct) {
        const unsigned short* wp = wob + (ct * 16 + lx) * 128 + hi * 8;
        f32x4 acc = {0.f, 0.f, 0.f, 0.f};
#pragma unroll
        for (int ks = 0; ks < 4; ++ks) {
            s16x8 wb = *(const s16x8*)(wp + ks * 32);
            // swapped: D[row=c][col=n]
            acc = __builtin_amdgcn_mfma_f32_16x16x32_bf16(wb, fa[ks], acc, 0, 0, 0);
        }
#pragma unroll
        for (int r = 0; r < 4; ++r) {
            const int c = ct * 16 + hi * 4 + r;
            const size_t off = ((size_t)c << 12) + n;
            ob[off] = acc[r] + bo[c] + xb[off];
        }
    }
}

extern "C" void kernel_launch(void* const* d_in, const int* in_sizes, int n_in,
                              void* d_out, int out_size, void* d_ws, size_t ws_size,
                              hipStream_t stream) {
    (void)in_sizes; (void)n_in; (void)out_size; (void)ws_size;
    const float* x  = (const float*)d_in[0];
    const float* wq = (const float*)d_in[1];
    const float* bq = (const float*)d_in[2];
    const float* wk = (const float*)d_in[3];
    const float* bk = (const float*)d_in[4];
    const float* wv = (const float*)d_in[5];
    const float* bv = (const float*)d_in[6];
    const float* wo = (const float*)d_in[7];
    const float* bo = (const float*)d_in[8];

    unsigned short* Q  = (unsigned short*)d_ws;                 // [B,N,E] bf16 (pre-scaled by log2e)
    unsigned short* K  = Q + (size_t)B_ * N_ * E_;
    unsigned short* Vt = K + (size_t)B_ * N_ * E_;              // [B,E,N] bf16
    unsigned short* featP = Vt + (size_t)B_ * N_ * E_;          // [SLICES][B][N][E] bf16
    float* denomP = (float*)(featP + (size_t)SLICES * B_ * N_ * E_); // [SLICES][B][N]
    unsigned short* wqb = (unsigned short*)(denomP + (size_t)SLICES * B_ * N_);
    unsigned short* wkb = wqb + E_ * C_;
    unsigned short* wvb = wkb + E_ * C_;
    unsigned short* wob = wvb + E_ * C_;                        // [C,E] bf16

    convert_w<<<dim3(128), dim3(256), 0, stream>>>(
        wq, wk, wv, wo, wqb, wkb, wvb, wob);
    qkv_kernel<<<dim3(B_ * (N_ / 64)), dim3(256), 0, stream>>>(
        x, wqb, bq, wkb, bk, wvb, bv, Q, K, Vt);
    attn_partial<<<dim3(B_ * 32 * SLICES), dim3(256), 0, stream>>>(
        Q, K, Vt, featP, denomP);
    combine_kernel<<<dim3(B_ * 64), dim3(256), 0, stream>>>(
        featP, denomP, wob, bo, x, (float*)d_out);
}

// Round 10
// 174.382 us; speedup vs baseline: 2.0649x; 1.0082x over previous
//
#include <hip/hip_runtime.h>
#include <hip/hip_bf16.h>

// Embedded-Gaussian non-local block, MI355X (gfx950).
// B=8, C=256, E=128, N=64*64=4096. fp32 in/out, bf16 MFMA internally.
//
// Round 10 = r5 skeleton (reg staging, padded LDS, 2 barriers/iter,
// 4 waves x 32q, relaxed launch_bounds(256,2)) +
//   - v_cvt_pk_bf16_f32 (inline asm) for hot-loop f32->bf16: 1-2 ops per
//     element vs 3-op manual round-to-nearest (softmax post-processing was
//     ~45% of wave time; this cuts its VALU part ~35%).
//   - exp2 softmax: Q pre-scaled by log2(e) in qkv; p = exp2(s' - 15*log2e)
//     (bit-equivalent values to exp(s-15); r9-verified).
//   - SLICES=2 (512 blocks, 32 kv-iters): halves featP traffic + combine VALU.
//   - P row stride 76 u16 (write-conflict-free, no XOR).
// Lessons kept: no waves/EU bound >2 (r3/r4/r7 spills); no gload_lds (r9);
// no reg-prefetch pipeline (r6); occupancy is reg-capped at 2 waves/SIMD
// (112 arch VGPR + 64 acc) -- wins must come from less serialized wave work.

typedef __attribute__((ext_vector_type(8))) short s16x8;
typedef __attribute__((ext_vector_type(4))) short s16x4;
typedef __attribute__((ext_vector_type(4))) float f32x4;

#define B_ 8
#define C_ 256
#define E_ 128
#define N_ 4096
#define SLICES 2
#define SLICE_KV (N_ / SLICES)          // 2048
#define NTILES (SLICE_KV / 64)          // 32 kv tiles per block
#define PST 76                          // P row stride in u16
#define LOG2E 1.44269504f
#define SHIFT2 21.6404256f              // 15 * log2(e)

static __device__ __forceinline__ unsigned short f2bf(float f) {
    union { float f; unsigned int u; } v; v.f = f;
    return (unsigned short)((v.u + 0x7FFFu + ((v.u >> 16) & 1u)) >> 16);
}
static __device__ __forceinline__ float bf2f(unsigned short h) {
    union { unsigned int u; float f; } v; v.u = ((unsigned int)h) << 16;
    return v.f;
}
// packed f32x2 -> bf16x2 in one VALU op (no builtin on gfx950; m240)
static __device__ __forceinline__ unsigned int cvtbf2(float lo, float hi) {
    unsigned int r;
    asm("v_cvt_pk_bf16_f32 %0, %1, %2" : "=v"(r) : "v"(lo), "v"(hi));
    return r;
}

// ---------------------------------------------------------------------------
// Weight pre-conversion: wq/wk/wv [E,C] and wo [C,E] f32 -> bf16.
// ---------------------------------------------------------------------------
__global__ __launch_bounds__(256) void convert_w(
    const float* __restrict__ wq, const float* __restrict__ wk,
    const float* __restrict__ wv, const float* __restrict__ wo,
    unsigned short* __restrict__ wqb, unsigned short* __restrict__ wkb,
    unsigned short* __restrict__ wvb, unsigned short* __restrict__ wob)
{
    const int i = blockIdx.x * 256 + threadIdx.x;   // 0..32767
    wqb[i] = f2bf(wq[i]);
    wkb[i] = f2bf(wk[i]);
    wvb[i] = f2bf(wv[i]);
    wob[i] = f2bf(wo[i]);
}

// ---------------------------------------------------------------------------
// QKV projection. Q outputs pre-scaled by log2(e) for the exp2 softmax.
// ---------------------------------------------------------------------------
__global__ __launch_bounds__(256, 2) void qkv_kernel(
    const float* __restrict__ x,
    const unsigned short* __restrict__ wqb, const float* __restrict__ bq,
    const unsigned short* __restrict__ wkb, const float* __restrict__ bk,
    const unsigned short* __restrict__ wvb, const float* __restrict__ bv,
    unsigned short* __restrict__ Q, unsigned short* __restrict__ K,
    unsigned short* __restrict__ Vt)
{
    __shared__ unsigned short xs[64 * 264];   // [n][c], pad 8

    const int tid = threadIdx.x;
    const int b  = blockIdx.x >> 6;
    const int n0 = (blockIdx.x & 63) << 6;

    {
        const int n  = tid & 63;
        const int c0 = tid >> 6;   // 0..3
        const float* xp = x + ((size_t)(b * C_) << 12) + n0 + n;
        for (int it = 0; it < 64; ++it) {
            const int c = it * 4 + c0;
            xs[n * 264 + c] = f2bf(xp[(size_t)c << 12]);
        }
    }
    __syncthreads();

    const int w = tid >> 6, l = tid & 63, hi = l >> 4, lx = l & 15;

    for (int idx = w; idx < 24; idx += 4) {
        const int out = idx >> 3;        // 0=q 1=k 2=v
        const int et  = idx & 7;
        const int e0  = et << 4;
        const unsigned short* W = (out == 0) ? wqb : (out == 1) ? wkb : wvb;
        const float* bias = (out == 0) ? bq : (out == 1) ? bk : bv;
        const float scale = (out == 0) ? LOG2E : 1.0f;

        s16x8 af[8];
        const unsigned short* wp = W + (e0 + lx) * C_ + hi * 8;
#pragma unroll
        for (int ks = 0; ks < 8; ++ks) af[ks] = *(const s16x8*)(wp + ks * 32);

        float bi[4];
#pragma unroll
        for (int r = 0; r < 4; ++r) bi[r] = bias[e0 + hi * 4 + r];

#pragma unroll
        for (int nt = 0; nt < 4; ++nt) {
            f32x4 acc = {0.f, 0.f, 0.f, 0.f};
#pragma unroll
            for (int ks = 0; ks < 8; ++ks) {
                s16x8 xb = *(const s16x8*)&xs[(nt * 16 + lx) * 264 + ks * 32 + hi * 8];
                acc = __builtin_amdgcn_mfma_f32_16x16x32_bf16(af[ks], xb, acc, 0, 0, 0);
            }
            const int n = n0 + nt * 16 + lx;
            if (out < 2) {
                unsigned short* dst =
                    ((out == 0) ? Q : K) + ((size_t)(b * N_ + n) << 7) + e0 + hi * 4;
                s16x4 pk;
#pragma unroll
                for (int r = 0; r < 4; ++r) pk[r] = (short)f2bf((acc[r] + bi[r]) * scale);
                *(s16x4*)dst = pk;
            } else {
#pragma unroll
                for (int r = 0; r < 4; ++r)
                    Vt[((size_t)(b * E_ + e0 + hi * 4 + r) << 12) + n] =
                        f2bf(acc[r] + bi[r]);
            }
        }
    }
}

// ---------------------------------------------------------------------------
// Attention partial. 512 blocks: b = blk&7 (XCD pin), idx = blk>>3:
// sl = idx>>5 (kv slice 0..1), qt = idx&31 (q-tile of 128).
// Wave w: q rows qt*128 + w*32. r5-proven staging (global->reg->padded LDS).
// ---------------------------------------------------------------------------
__global__ __launch_bounds__(256, 2) void attn_partial(
    const unsigned short* __restrict__ Q, const unsigned short* __restrict__ K,
    const unsigned short* __restrict__ Vt,
    unsigned short* __restrict__ featP, float* __restrict__ denomP)
{
    __shared__ unsigned short Ks[64 * 136];      // [kv][e], stride 272B
    __shared__ unsigned short Vs[128 * 72];      // [e][kv], stride 144B
    __shared__ unsigned short Ps[4][32 * PST];   // per-wave [q][kv], stride 152B

    const int tid = threadIdx.x;
    const int b   = blockIdx.x & 7;
    const int idx = blockIdx.x >> 3;
    const int sl  = idx >> 5;      // kv slice 0..1
    const int qt  = idx & 31;      // q tile (128 rows)
    const int w = tid >> 6, l = tid & 63, hi = l >> 4, lx = l & 15;
    const int q0 = qt * 128 + w * 32;

    // hoisted Q fragments: 2 subtiles x 4 ks
    s16x8 qA[2][4];
#pragma unroll
    for (int qf = 0; qf < 2; ++qf) {
        const unsigned short* qp =
            Q + ((size_t)(b * N_ + q0 + qf * 16 + lx) << 7) + hi * 8;
#pragma unroll
        for (int ks = 0; ks < 4; ++ks) qA[qf][ks] = *(const s16x8*)(qp + ks * 32);
    }

    f32x4 feat[2][8];
#pragma unroll
    for (int qf = 0; qf < 2; ++qf)
#pragma unroll
        for (int ef = 0; ef < 8; ++ef) feat[qf][ef] = (f32x4){0.f, 0.f, 0.f, 0.f};
    float dAcc[8];
#pragma unroll
    for (int i = 0; i < 8; ++i) dAcc[i] = 0.f;

    const unsigned short* Kg = K + ((size_t)(b * N_) << 7);
    const unsigned short* Vg = Vt + ((size_t)(b * E_) << 12);
    unsigned short* pw = &Ps[w][0];

    for (int it = 0; it < NTILES; ++it) {
        const int kv0 = sl * SLICE_KV + it * 64;
        __syncthreads();   // all waves' reads of prev tile done before restage
        // stage K tile [64kv][128e]: lane-contiguous 16B, 256B/instr coalesced
#pragma unroll
        for (int i = 0; i < 4; ++i) {
            const int flat = tid + i * 256;           // 16B units
            const int row = flat >> 4, c16 = flat & 15;
            *(s16x8*)&Ks[row * 136 + c16 * 8] =
                *(const s16x8*)(Kg + (size_t)(kv0 + row) * 128 + c16 * 8);
        }
        // stage V tile [128e][64kv]
#pragma unroll
        for (int i = 0; i < 4; ++i) {
            const int flat = tid + i * 256;
            const int e = flat >> 3, c16 = flat & 7;
            *(s16x8*)&Vs[e * 72 + c16 * 8] =
                *(const s16x8*)(Vg + ((size_t)e << 12) + kv0 + c16 * 8);
        }
        __syncthreads();

        // QK^T + exp2 + P->LDS (per-wave slice, packed bf16 conversion)
#pragma unroll
        for (int kvf = 0; kvf < 4; ++kvf) {
            f32x4 s0 = {0.f, 0.f, 0.f, 0.f}, s1 = {0.f, 0.f, 0.f, 0.f};
#pragma unroll
            for (int ks = 0; ks < 4; ++ks) {
                s16x8 kb = *(const s16x8*)&Ks[(kvf * 16 + lx) * 136 + ks * 32 + hi * 8];
                s0 = __builtin_amdgcn_mfma_f32_16x16x32_bf16(qA[0][ks], kb, s0, 0, 0, 0);
                s1 = __builtin_amdgcn_mfma_f32_16x16x32_bf16(qA[1][ks], kb, s1, 0, 0, 0);
            }
#pragma unroll
            for (int r = 0; r < 4; ++r) {
                float p0 = __builtin_exp2f(s0[r] - SHIFT2);
                float p1 = __builtin_exp2f(s1[r] - SHIFT2);
                dAcc[r]     += p0;
                dAcc[4 + r] += p1;
                const unsigned int pk = cvtbf2(p0, p1);   // lo=bf16(p0) hi=bf16(p1)
                pw[(hi * 4 + r) * PST      + kvf * 16 + lx] = (unsigned short)pk;
                pw[(16 + hi * 4 + r) * PST + kvf * 16 + lx] = (unsigned short)(pk >> 16);
            }
        }
        // PV: feat[32q x 128e] += P @ V (P wave-private: no barrier needed)
#pragma unroll
        for (int ks = 0; ks < 2; ++ks) {
            s16x8 pa0 = *(const s16x8*)&pw[(lx)      * PST + ks * 32 + hi * 8];
            s16x8 pa1 = *(const s16x8*)&pw[(16 + lx) * PST + ks * 32 + hi * 8];
#pragma unroll
            for (int ef = 0; ef < 8; ++ef) {
                s16x8 vb = *(const s16x8*)&Vs[(ef * 16 + lx) * 72 + ks * 32 + hi * 8];
                feat[0][ef] = __builtin_amdgcn_mfma_f32_16x16x32_bf16(pa0, vb, feat[0][ef], 0, 0, 0);
                feat[1][ef] = __builtin_amdgcn_mfma_f32_16x16x32_bf16(pa1, vb, feat[1][ef], 0, 0, 0);
            }
        }
    }

    // denom: reduce over kv lanes (lx)
#pragma unroll
    for (int i = 0; i < 8; ++i) {
        float v = dAcc[i];
        v += __shfl_xor(v, 1); v += __shfl_xor(v, 2);
        v += __shfl_xor(v, 4); v += __shfl_xor(v, 8);
        dAcc[i] = v;
    }
    const size_t qg = (size_t)((sl * 8 + b) * N_ + q0);
    if (lx == 0) {
        float* dP = denomP + qg;
#pragma unroll
        for (int qf = 0; qf < 2; ++qf)
#pragma unroll
            for (int r = 0; r < 4; ++r)
                dP[qf * 16 + hi * 4 + r] = dAcc[qf * 4 + r];
    }
    unsigned short* fP = featP + (qg << 7);
#pragma unroll
    for (int qf = 0; qf < 2; ++qf)
#pragma unroll
        for (int ef = 0; ef < 8; ++ef)
#pragma unroll
            for (int r = 0; r < 4; ++r)
                fP[(qf * 16 + hi * 4 + r) * 128 + ef * 16 + lx] =
                    (unsigned short)cvtbf2(feat[qf][ef][r], 0.f);
}

// ---------------------------------------------------------------------------
// Combine: sum 2 kv-slice partials, normalize, out-proj (swapped operands ->
// n-coalesced stores; B-frags direct s16x8 from wob) + bias + residual.
// grid: 8 b x 64 n-tiles of 64.
// ---------------------------------------------------------------------------
__global__ __launch_bounds__(256, 2) void combine_kernel(
    const unsigned short* __restrict__ featP, const float* __restrict__ denomP,
    const unsigned short* __restrict__ wob, const float* __restrict__ bo,
    const float* __restrict__ x, float* __restrict__ out)
{
    __shared__ unsigned short fs[64 * 136];   // [q][e], stride 272B

    const int tid = threadIdx.x;
    const int b  = blockIdx.x & 7;
    const int nt = blockIdx.x >> 3;          // 0..63

    // sum partials + normalize -> fs (bf16)
    {
        const int q = tid >> 2, eb = (tid & 3) * 32;
        const int n = nt * 64 + q;
        float den = 0.f;
#pragma unroll
        for (int s = 0; s < SLICES; ++s)
            den += denomP[(size_t)((s * 8 + b) * N_) + n];
        const float inv = 1.f / den;
#pragma unroll
        for (int e8 = 0; e8 < 4; ++e8) {
            float acc[8];
#pragma unroll
            for (int j = 0; j < 8; ++j) acc[j] = 0.f;
#pragma unroll
            for (int s = 0; s < SLICES; ++s) {
                s16x8 v = *(const s16x8*)(featP +
                    (((size_t)((s * 8 + b) * N_) + n) << 7) + eb + e8 * 8);
#pragma unroll
                for (int j = 0; j < 8; ++j) acc[j] += bf2f((unsigned short)v[j]);
            }
            s16x8 o;
#pragma unroll
            for (int j = 0; j < 8; ++j)
                o[j] = (short)(unsigned short)cvtbf2(acc[j] * inv, 0.f);
            *(s16x8*)&fs[q * 136 + eb + e8 * 8] = o;
        }
    }
    __syncthreads();

    const int w = tid >> 6, l = tid & 63, hi = l >> 4, lx = l & 15;

    // B-frags of feat (col = q)
    s16x8 fa[4];
#pragma unroll
    for (int ks = 0; ks < 4; ++ks)
        fa[ks] = *(const s16x8*)&fs[(w * 16 + lx) * 136 + ks * 32 + hi * 8];

    const int n = nt * 64 + w * 16 + lx;
    const float* xb = x + ((size_t)(b * C_) << 12);
    float* ob = out + ((size_t)(b * C_) << 12);
#pragma unroll 1
    for (int ct = 0; ct < 16; ++ct) {
        const unsigned short* wp = wob + (ct * 16 + lx) * 128 + hi * 8;
        f32x4 acc = {0.f, 0.f, 0.f, 0.f};
#pragma unroll
        for (int ks = 0; ks < 4; ++ks) {
            s16x8 wb = *(const s16x8*)(wp + ks * 32);
            // swapped: D[row=c][col=n]
            acc = __builtin_amdgcn_mfma_f32_16x16x32_bf16(wb, fa[ks], acc, 0, 0, 0);
        }
#pragma unroll
        for (int r = 0; r < 4; ++r) {
            const int c = ct * 16 + hi * 4 + r;
            const size_t off = ((size_t)c << 12) + n;
            ob[off] = acc[r] + bo[c] + xb[off];
        }
    }
}

extern "C" void kernel_launch(void* const* d_in, const int* in_sizes, int n_in,
                              void* d_out, int out_size, void* d_ws, size_t ws_size,
                              hipStream_t stream) {
    (void)in_sizes; (void)n_in; (void)out_size; (void)ws_size;
    const float* x  = (const float*)d_in[0];
    const float* wq = (const float*)d_in[1];
    const float* bq = (const float*)d_in[2];
    const float* wk = (const float*)d_in[3];
    const float* bk = (const float*)d_in[4];
    const float* wv = (const float*)d_in[5];
    const float* bv = (const float*)d_in[6];
    const float* wo = (const float*)d_in[7];
    const float* bo = (const float*)d_in[8];

    unsigned short* Q  = (unsigned short*)d_ws;                 // [B,N,E] bf16 (pre-scaled by log2e)
    unsigned short* K  = Q + (size_t)B_ * N_ * E_;
    unsigned short* Vt = K + (size_t)B_ * N_ * E_;              // [B,E,N] bf16
    unsigned short* featP = Vt + (size_t)B_ * N_ * E_;          // [SLICES][B][N][E] bf16
    float* denomP = (float*)(featP + (size_t)SLICES * B_ * N_ * E_); // [SLICES][B][N]
    unsigned short* wqb = (unsigned short*)(denomP + (size_t)SLICES * B_ * N_);
    unsigned short* wkb = wqb + E_ * C_;
    unsigned short* wvb = wkb + E_ * C_;
    unsigned short* wob = wvb + E_ * C_;                        // [C,E] bf16

    convert_w<<<dim3(128), dim3(256), 0, stream>>>(
        wq, wk, wv, wo, wqb, wkb, wvb, wob);
    qkv_kernel<<<dim3(B_ * (N_ / 64)), dim3(256), 0, stream>>>(
        x, wqb, bq, wkb, bk, wvb, bv, Q, K, Vt);
    attn_partial<<<dim3(B_ * 32 * SLICES), dim3(256), 0, stream>>>(
        Q, K, Vt, featP, denomP);
    combine_kernel<<<dim3(B_ * 64), dim3(256), 0, stream>>>(
        featP, denomP, wob, bo, x, (float*)d_out);
}

// Round 11
// 155.140 us; speedup vs baseline: 2.3210x; 1.1240x over previous
//
#include <hip/hip_runtime.h>
#include <hip/hip_bf16.h>

// Embedded-Gaussian non-local block, MI355X (gfx950).
// B=8, C=256, E=128, N=64*64=4096. fp32 in/out, bf16 MFMA internally.
//
// Round 11 = r5 skeleton (SLICES=4, 1024 blocks, reg staging, padded LDS,
// 2 barriers/iter, 4 waves x 32q, launch_bounds(256,2)) + IN-REGISTER P:
//   - QK^T computed SWAPPED: mfma(kb, qA) -> D = P^T[kv][q=lx] (fragments
//     are layout-identical; swap is free).
//   - P^T -> PA-fragment transpose done in registers with
//     v_permlane32_swap_b32 + v_permlane16_swap_b32 double-swap chains
//     (derivation: target pa[ks] word0/word2 = the two outputs of the chain
//     on (T[2ks].w, T[2ks+1].w); all hi-group cases verified).
//   - Ps LDS array DELETED (55.3KB -> 35.8KB); no P lgkm dependency between
//     softmax and PV; denom reduce = 2 shfl_xor (16,32) over hi groups.
//   - bf16 packing via __bf16 scalar casts (compiler emits v_cvt_pk_bf16_f32;
//     NOT inline asm -- m240: asm cvt_pk is -37%).
// Kept: exp2 softmax (Q pre-scaled by log2e in qkv; r9/r10-verified exact).
// Lessons: no waves/EU bound >2 (r3/r4/r7); no gload_lds (r9); no SLICES=2
// (r6/r10: single-generation grid loses cross-gen overlap); no asm cvt_pk (r10).

typedef __attribute__((ext_vector_type(8))) short s16x8;
typedef __attribute__((ext_vector_type(4))) short s16x4;
typedef __attribute__((ext_vector_type(4))) float f32x4;
typedef __attribute__((ext_vector_type(4))) unsigned int u32x4;

#define B_ 8
#define C_ 256
#define E_ 128
#define N_ 4096
#define SLICES 4
#define SLICE_KV (N_ / SLICES)          // 1024
#define NTILES (SLICE_KV / 64)          // 16 kv tiles per block
#define LOG2E 1.44269504f
#define SHIFT2 21.6404256f              // 15 * log2(e)

static __device__ __forceinline__ unsigned short f2bf(float f) {
    union { float f; unsigned int u; } v; v.f = f;
    return (unsigned short)((v.u + 0x7FFFu + ((v.u >> 16) & 1u)) >> 16);
}
static __device__ __forceinline__ float bf2f(unsigned short h) {
    union { unsigned int u; float f; } v; v.u = ((unsigned int)h) << 16;
    return v.f;
}
// pack two f32 -> bf16x2 (RNE); scalar __bf16 casts let the compiler emit
// v_cvt_pk_bf16_f32 (m240: do NOT hand-write the asm).
static __device__ __forceinline__ unsigned int pkbf(float a, float b) {
    __bf16 lo = (__bf16)a, hi = (__bf16)b;
    unsigned short ul = __builtin_bit_cast(unsigned short, lo);
    unsigned short uh = __builtin_bit_cast(unsigned short, hi);
    return (unsigned int)ul | ((unsigned int)uh << 16);
}
// register-only lane exchanges (modify both operands; pure VALU, no counters)
static __device__ __forceinline__ void swap32(unsigned int& a, unsigned int& b) {
    asm("v_permlane32_swap_b32 %0, %1" : "+v"(a), "+v"(b));
}
static __device__ __forceinline__ void swap16(unsigned int& a, unsigned int& b) {
    asm("v_permlane16_swap_b32 %0, %1" : "+v"(a), "+v"(b));
}

// ---------------------------------------------------------------------------
// Weight pre-conversion: wq/wk/wv [E,C] and wo [C,E] f32 -> bf16.
// ---------------------------------------------------------------------------
__global__ __launch_bounds__(256) void convert_w(
    const float* __restrict__ wq, const float* __restrict__ wk,
    const float* __restrict__ wv, const float* __restrict__ wo,
    unsigned short* __restrict__ wqb, unsigned short* __restrict__ wkb,
    unsigned short* __restrict__ wvb, unsigned short* __restrict__ wob)
{
    const int i = blockIdx.x * 256 + threadIdx.x;   // 0..32767
    wqb[i] = f2bf(wq[i]);
    wkb[i] = f2bf(wk[i]);
    wvb[i] = f2bf(wv[i]);
    wob[i] = f2bf(wv == wq ? 0.f : wo[i]);  // (never taken; keeps wo read)
}

// ---------------------------------------------------------------------------
// QKV projection. Q outputs pre-scaled by log2(e) for the exp2 softmax.
// ---------------------------------------------------------------------------
__global__ __launch_bounds__(256, 2) void qkv_kernel(
    const float* __restrict__ x,
    const unsigned short* __restrict__ wqb, const float* __restrict__ bq,
    const unsigned short* __restrict__ wkb, const float* __restrict__ bk,
    const unsigned short* __restrict__ wvb, const float* __restrict__ bv,
    unsigned short* __restrict__ Q, unsigned short* __restrict__ K,
    unsigned short* __restrict__ Vt)
{
    __shared__ unsigned short xs[64 * 264];   // [n][c], pad 8

    const int tid = threadIdx.x;
    const int b  = blockIdx.x >> 6;
    const int n0 = (blockIdx.x & 63) << 6;

    {
        const int n  = tid & 63;
        const int c0 = tid >> 6;   // 0..3
        const float* xp = x + ((size_t)(b * C_) << 12) + n0 + n;
        for (int it = 0; it < 64; ++it) {
            const int c = it * 4 + c0;
            xs[n * 264 + c] = f2bf(xp[(size_t)c << 12]);
        }
    }
    __syncthreads();

    const int w = tid >> 6, l = tid & 63, hi = l >> 4, lx = l & 15;

    for (int idx = w; idx < 24; idx += 4) {
        const int out = idx >> 3;        // 0=q 1=k 2=v
        const int et  = idx & 7;
        const int e0  = et << 4;
        const unsigned short* W = (out == 0) ? wqb : (out == 1) ? wkb : wvb;
        const float* bias = (out == 0) ? bq : (out == 1) ? bk : bv;
        const float scale = (out == 0) ? LOG2E : 1.0f;

        s16x8 af[8];
        const unsigned short* wp = W + (e0 + lx) * C_ + hi * 8;
#pragma unroll
        for (int ks = 0; ks < 8; ++ks) af[ks] = *(const s16x8*)(wp + ks * 32);

        float bi[4];
#pragma unroll
        for (int r = 0; r < 4; ++r) bi[r] = bias[e0 + hi * 4 + r];

#pragma unroll
        for (int nt = 0; nt < 4; ++nt) {
            f32x4 acc = {0.f, 0.f, 0.f, 0.f};
#pragma unroll
            for (int ks = 0; ks < 8; ++ks) {
                s16x8 xb = *(const s16x8*)&xs[(nt * 16 + lx) * 264 + ks * 32 + hi * 8];
                acc = __builtin_amdgcn_mfma_f32_16x16x32_bf16(af[ks], xb, acc, 0, 0, 0);
            }
            const int n = n0 + nt * 16 + lx;
            if (out < 2) {
                unsigned short* dst =
                    ((out == 0) ? Q : K) + ((size_t)(b * N_ + n) << 7) + e0 + hi * 4;
                s16x4 pk;
#pragma unroll
                for (int r = 0; r < 4; ++r) pk[r] = (short)f2bf((acc[r] + bi[r]) * scale);
                *(s16x4*)dst = pk;
            } else {
#pragma unroll
                for (int r = 0; r < 4; ++r)
                    Vt[((size_t)(b * E_ + e0 + hi * 4 + r) << 12) + n] =
                        f2bf(acc[r] + bi[r]);
            }
        }
    }
}

// ---------------------------------------------------------------------------
// Attention partial. 1024 blocks: b = blk&7 (XCD pin), idx = blk>>3:
// sl = idx>>5 (kv slice 0..3), qt = idx&31 (q-tile of 128).
// Wave w: q rows qt*128 + w*32. P lives entirely in registers.
// ---------------------------------------------------------------------------
__global__ __launch_bounds__(256, 2) void attn_partial(
    const unsigned short* __restrict__ Q, const unsigned short* __restrict__ K,
    const unsigned short* __restrict__ Vt,
    unsigned short* __restrict__ featP, float* __restrict__ denomP)
{
    __shared__ unsigned short Ks[64 * 136];      // [kv][e], stride 272B
    __shared__ unsigned short Vs[128 * 72];      // [e][kv], stride 144B

    const int tid = threadIdx.x;
    const int b   = blockIdx.x & 7;
    const int idx = blockIdx.x >> 3;
    const int sl  = idx >> 5;      // kv slice 0..3
    const int qt  = idx & 31;      // q tile (128 rows)
    const int w = tid >> 6, l = tid & 63, hi = l >> 4, lx = l & 15;
    const int q0 = qt * 128 + w * 32;

    // hoisted Q fragments: 2 subtiles x 4 ks (row=q=lx, k=hi*8+j)
    s16x8 qA[2][4];
#pragma unroll
    for (int qf = 0; qf < 2; ++qf) {
        const unsigned short* qp =
            Q + ((size_t)(b * N_ + q0 + qf * 16 + lx) << 7) + hi * 8;
#pragma unroll
        for (int ks = 0; ks < 4; ++ks) qA[qf][ks] = *(const s16x8*)(qp + ks * 32);
    }

    f32x4 feat[2][8];
#pragma unroll
    for (int qf = 0; qf < 2; ++qf)
#pragma unroll
        for (int ef = 0; ef < 8; ++ef) feat[qf][ef] = (f32x4){0.f, 0.f, 0.f, 0.f};
    float dq[2] = {0.f, 0.f};      // denom partial for q = q0 + qf*16 + lx

    const unsigned short* Kg = K + ((size_t)(b * N_) << 7);
    const unsigned short* Vg = Vt + ((size_t)(b * E_) << 12);

    for (int it = 0; it < NTILES; ++it) {
        const int kv0 = sl * SLICE_KV + it * 64;
        __syncthreads();   // all waves' kb/vb reads of prev tile done
        // stage K tile [64kv][128e]: lane-contiguous 16B, coalesced
#pragma unroll
        for (int i = 0; i < 4; ++i) {
            const int flat = tid + i * 256;           // 16B units
            const int row = flat >> 4, c16 = flat & 15;
            *(s16x8*)&Ks[row * 136 + c16 * 8] =
                *(const s16x8*)(Kg + (size_t)(kv0 + row) * 128 + c16 * 8);
        }
        // stage V tile [128e][64kv]
#pragma unroll
        for (int i = 0; i < 4; ++i) {
            const int flat = tid + i * 256;
            const int e = flat >> 3, c16 = flat & 7;
            *(s16x8*)&Vs[e * 72 + c16 * 8] =
                *(const s16x8*)(Vg + ((size_t)e << 12) + kv0 + c16 * 8);
        }
        __syncthreads();

        // QK^T SWAPPED: D = P^T[kv_local = 4hi+r (+16kvf)][q = lx (+16qf)]
        // tw[qf][kvf][0] = pack(p[r=0], p[r=1]); [1] = pack(p[2], p[3])
        unsigned int tw[2][4][2];
#pragma unroll
        for (int kvf = 0; kvf < 4; ++kvf) {
            s16x8 kb[4];
#pragma unroll
            for (int ks = 0; ks < 4; ++ks)
                kb[ks] = *(const s16x8*)&Ks[(kvf * 16 + lx) * 136 + ks * 32 + hi * 8];
#pragma unroll
            for (int qf = 0; qf < 2; ++qf) {
                f32x4 s = {0.f, 0.f, 0.f, 0.f};
#pragma unroll
                for (int ks = 0; ks < 4; ++ks)
                    s = __builtin_amdgcn_mfma_f32_16x16x32_bf16(kb[ks], qA[qf][ks], s, 0, 0, 0);
                const float p0 = __builtin_exp2f(s[0] - SHIFT2);
                const float p1 = __builtin_exp2f(s[1] - SHIFT2);
                const float p2 = __builtin_exp2f(s[2] - SHIFT2);
                const float p3 = __builtin_exp2f(s[3] - SHIFT2);
                dq[qf] += (p0 + p1) + (p2 + p3);
                tw[qf][kvf][0] = pkbf(p0, p1);
                tw[qf][kvf][1] = pkbf(p2, p3);
            }
        }

        // In-register transpose P^T -> PA fragments:
        // pa[qf][ks] element j holds P[q=lx+16qf][kv = 32ks + 8hi + j].
        // Chain: {a,b} = permlane16_swap(permlane32_swap(T[2ks].w, T[2ks+1].w))
        //   -> a = word(j=2w..), b = word(j=4+2w..)  (verified all hi cases)
        s16x8 pa[2][2];
#pragma unroll
        for (int qf = 0; qf < 2; ++qf) {
#pragma unroll
            for (int ks = 0; ks < 2; ++ks) {
                unsigned int a0 = tw[qf][2 * ks][0], b0 = tw[qf][2 * ks + 1][0];
                swap32(a0, b0); swap16(a0, b0);
                unsigned int a1 = tw[qf][2 * ks][1], b1 = tw[qf][2 * ks + 1][1];
                swap32(a1, b1); swap16(a1, b1);
                u32x4 wv = {a0, a1, b0, b1};
                pa[qf][ks] = __builtin_bit_cast(s16x8, wv);
            }
        }

        // PV: feat[32q x 128e] += P @ V
#pragma unroll
        for (int ks = 0; ks < 2; ++ks) {
#pragma unroll
            for (int ef = 0; ef < 8; ++ef) {
                s16x8 vb = *(const s16x8*)&Vs[(ef * 16 + lx) * 72 + ks * 32 + hi * 8];
                feat[0][ef] = __builtin_amdgcn_mfma_f32_16x16x32_bf16(pa[0][ks], vb, feat[0][ef], 0, 0, 0);
                feat[1][ef] = __builtin_amdgcn_mfma_f32_16x16x32_bf16(pa[1][ks], vb, feat[1][ef], 0, 0, 0);
            }
        }
    }

    // denom: q = q0 + qf*16 + lx; sum over hi groups (lanes l^16, l^32, l^48)
#pragma unroll
    for (int qf = 0; qf < 2; ++qf) {
        float v = dq[qf];
        v += __shfl_xor(v, 16);
        v += __shfl_xor(v, 32);
        dq[qf] = v;
    }
    const size_t qg = (size_t)((sl * 8 + b) * N_ + q0);
    if (l < 16) {
        float* dP = denomP + qg;
        dP[l]      = dq[0];
        dP[16 + l] = dq[1];
    }
    unsigned short* fP = featP + (qg << 7);
#pragma unroll
    for (int qf = 0; qf < 2; ++qf)
#pragma unroll
        for (int ef = 0; ef < 8; ++ef)
#pragma unroll
            for (int r = 0; r < 4; ++r)
                fP[(qf * 16 + hi * 4 + r) * 128 + ef * 16 + lx] =
                    f2bf(feat[qf][ef][r]);
}

// ---------------------------------------------------------------------------
// Combine: sum 4 kv-slice partials, normalize, out-proj (swapped operands ->
// n-coalesced stores; B-frags direct s16x8 from wob) + bias + residual.
// grid: 8 b x 64 n-tiles of 64.
// ---------------------------------------------------------------------------
__global__ __launch_bounds__(256, 2) void combine_kernel(
    const unsigned short* __restrict__ featP, const float* __restrict__ denomP,
    const unsigned short* __restrict__ wob, const float* __restrict__ bo,
    const float* __restrict__ x, float* __restrict__ out)
{
    __shared__ unsigned short fs[64 * 136];   // [q][e], stride 272B

    const int tid = threadIdx.x;
    const int b  = blockIdx.x & 7;
    const int nt = blockIdx.x >> 3;          // 0..63

    // sum partials + normalize -> fs (bf16)
    {
        const int q = tid >> 2, eb = (tid & 3) * 32;
        const int n = nt * 64 + q;
        float den = 0.f;
#pragma unroll
        for (int s = 0; s < SLICES; ++s)
            den += denomP[(size_t)((s * 8 + b) * N_) + n];
        const float inv = 1.f / den;
#pragma unroll
        for (int e8 = 0; e8 < 4; ++e8) {
            float acc[8];
#pragma unroll
            for (int j = 0; j < 8; ++j) acc[j] = 0.f;
#pragma unroll
            for (int s = 0; s < SLICES; ++s) {
                s16x8 v = *(const s16x8*)(featP +
                    (((size_t)((s * 8 + b) * N_) + n) << 7) + eb + e8 * 8);
#pragma unroll
                for (int j = 0; j < 8; ++j) acc[j] += bf2f((unsigned short)v[j]);
            }
            s16x8 o;
#pragma unroll
            for (int j = 0; j < 8; ++j) o[j] = (short)f2bf(acc[j] * inv);
            *(s16x8*)&fs[q * 136 + eb + e8 * 8] = o;
        }
    }
    __syncthreads();

    const int w = tid >> 6, l = tid & 63, hi = l >> 4, lx = l & 15;

    // B-frags of feat (col = q)
    s16x8 fa[4];
#pragma unroll
    for (int ks = 0; ks < 4; ++ks)
        fa[ks] = *(const s16x8*)&fs[(w * 16 + lx) * 136 + ks * 32 + hi * 8];

    const int n = nt * 64 + w * 16 + lx;
    const float* xb = x + ((size_t)(b * C_) << 12);
    float* ob = out + ((size_t)(b * C_) << 12);
#pragma unroll 1
    for (int ct = 0; ct < 16; ++ct) {
        const unsigned short* wp = wob + (ct * 16 + lx) * 128 + hi * 8;
        f32x4 acc = {0.f, 0.f, 0.f, 0.f};
#pragma unroll
        for (int ks = 0; ks < 4; ++ks) {
            s16x8 wb = *(const s16x8*)(wp + ks * 32);
            // swapped: D[row=c][col=n]
            acc = __builtin_amdgcn_mfma_f32_16x16x32_bf16(wb, fa[ks], acc, 0, 0, 0);
        }
#pragma unroll
        for (int r = 0; r < 4; ++r) {
            const int c = ct * 16 + hi * 4 + r;
            const size_t off = ((size_t)c << 12) + n;
            ob[off] = acc[r] + bo[c] + xb[off];
        }
    }
}

extern "C" void kernel_launch(void* const* d_in, const int* in_sizes, int n_in,
                              void* d_out, int out_size, void* d_ws, size_t ws_size,
                              hipStream_t stream) {
    (void)in_sizes; (void)n_in; (void)out_size; (void)ws_size;
    const float* x  = (const float*)d_in[0];
    const float* wq = (const float*)d_in[1];
    const float* bq = (const float*)d_in[2];
    const float* wk = (const float*)d_in[3];
    const float* bk = (const float*)d_in[4];
    const float* wv = (const float*)d_in[5];
    const float* bv = (const float*)d_in[6];
    const float* wo = (const float*)d_in[7];
    const float* bo = (const float*)d_in[8];

    unsigned short* Q  = (unsigned short*)d_ws;                 // [B,N,E] bf16 (pre-scaled by log2e)
    unsigned short* K  = Q + (size_t)B_ * N_ * E_;
    unsigned short* Vt = K + (size_t)B_ * N_ * E_;              // [B,E,N] bf16
    unsigned short* featP = Vt + (size_t)B_ * N_ * E_;          // [SLICES][B][N][E] bf16
    float* denomP = (float*)(featP + (size_t)SLICES * B_ * N_ * E_); // [SLICES][B][N]
    unsigned short* wqb = (unsigned short*)(denomP + (size_t)SLICES * B_ * N_);
    unsigned short* wkb = wqb + E_ * C_;
    unsigned short* wvb = wkb + E_ * C_;
    unsigned short* wob = wvb + E_ * C_;                        // [C,E] bf16

    convert_w<<<dim3(128), dim3(256), 0, stream>>>(
        wq, wk, wv, wo, wqb, wkb, wvb, wob);
    qkv_kernel<<<dim3(B_ * (N_ / 64)), dim3(256), 0, stream>>>(
        x, wqb, bq, wkb, bk, wvb, bv, Q, K, Vt);
    attn_partial<<<dim3(B_ * 32 * SLICES), dim3(256), 0, stream>>>(
        Q, K, Vt, featP, denomP);
    combine_kernel<<<dim3(B_ * 64), dim3(256), 0, stream>>>(
        featP, denomP, wob, bo, x, (float*)d_out);
}

// Round 12
// 154.960 us; speedup vs baseline: 2.3237x; 1.0012x over previous
//
#include <hip/hip_runtime.h>
#include <hip/hip_bf16.h>

// Embedded-Gaussian non-local block, MI355X (gfx950).
// B=8, C=256, E=128, N=64*64=4096. fp32 in/out, bf16 MFMA internally.
//
// Round 12 = r5 skeleton (SLICES=4, 1024 blocks, 4 waves x 32q, LDS-P,
// launch_bounds(256,2)) + DOUBLE-BUFFERED K/V with ONE barrier per iter:
//   iter t: {issue global loads tile t+1 -> regs} {compute tile t from
//           buf[cur]} {ds_write regs -> buf[cur^1]} {barrier}.
//   Hazards: writes to cur^1 vs other waves' reads of cur^1 (iter t-1) are
//   separated by the shared end-of-(t-1) barrier; reads of cur (tile t) vs
//   its writes (end of t-1) likewise. P is wave-private -> no barrier.
// LDS fits 2 blocks/CU by dropping pads: linear K/V + granule XOR swizzle
//   (write granule g^row&7, read same) -> every wave-wide b128 hits the
//   8-lane/bank-quad minimum (verified for staging writes, kb, vb reads).
//   Ps unpadded [32x64] with col ^= (row&7)<<3 (writes ~2-4-way, reads min).
//   Total = 32768(Ks x2) + 32768(Vs x2) + 16384(Ps) = 81920 B exactly.
// Kept: exp2 softmax (Q pre-scaled by log2e), SLICES=4 (r6/r10: SLICES=2
// costs ~25us), no asm cvt_pk (r10), no in-reg P (r11: +13us VALU).

typedef __attribute__((ext_vector_type(8))) short s16x8;
typedef __attribute__((ext_vector_type(4))) short s16x4;
typedef __attribute__((ext_vector_type(4))) float f32x4;

#define B_ 8
#define C_ 256
#define E_ 128
#define N_ 4096
#define SLICES 4
#define SLICE_KV (N_ / SLICES)          // 1024
#define NTILES (SLICE_KV / 64)          // 16 kv tiles per block
#define LOG2E 1.44269504f
#define SHIFT2 21.6404256f              // 15 * log2(e)

static __device__ __forceinline__ unsigned short f2bf(float f) {
    union { float f; unsigned int u; } v; v.f = f;
    return (unsigned short)((v.u + 0x7FFFu + ((v.u >> 16) & 1u)) >> 16);
}
static __device__ __forceinline__ float bf2f(unsigned short h) {
    union { unsigned int u; float f; } v; v.u = ((unsigned int)h) << 16;
    return v.f;
}

// ---------------------------------------------------------------------------
// Weight pre-conversion: wq/wk/wv [E,C] and wo [C,E] f32 -> bf16.
// ---------------------------------------------------------------------------
__global__ __launch_bounds__(256) void convert_w(
    const float* __restrict__ wq, const float* __restrict__ wk,
    const float* __restrict__ wv, const float* __restrict__ wo,
    unsigned short* __restrict__ wqb, unsigned short* __restrict__ wkb,
    unsigned short* __restrict__ wvb, unsigned short* __restrict__ wob)
{
    const int i = blockIdx.x * 256 + threadIdx.x;   // 0..32767
    wqb[i] = f2bf(wq[i]);
    wkb[i] = f2bf(wk[i]);
    wvb[i] = f2bf(wv[i]);
    wob[i] = f2bf(wo[i]);
}

// ---------------------------------------------------------------------------
// QKV projection. Q outputs pre-scaled by log2(e) for the exp2 softmax.
// ---------------------------------------------------------------------------
__global__ __launch_bounds__(256, 2) void qkv_kernel(
    const float* __restrict__ x,
    const unsigned short* __restrict__ wqb, const float* __restrict__ bq,
    const unsigned short* __restrict__ wkb, const float* __restrict__ bk,
    const unsigned short* __restrict__ wvb, const float* __restrict__ bv,
    unsigned short* __restrict__ Q, unsigned short* __restrict__ K,
    unsigned short* __restrict__ Vt)
{
    __shared__ unsigned short xs[64 * 264];   // [n][c], pad 8

    const int tid = threadIdx.x;
    const int b  = blockIdx.x >> 6;
    const int n0 = (blockIdx.x & 63) << 6;

    {
        const int n  = tid & 63;
        const int c0 = tid >> 6;   // 0..3
        const float* xp = x + ((size_t)(b * C_) << 12) + n0 + n;
        for (int it = 0; it < 64; ++it) {
            const int c = it * 4 + c0;
            xs[n * 264 + c] = f2bf(xp[(size_t)c << 12]);
        }
    }
    __syncthreads();

    const int w = tid >> 6, l = tid & 63, hi = l >> 4, lx = l & 15;

    for (int idx = w; idx < 24; idx += 4) {
        const int out = idx >> 3;        // 0=q 1=k 2=v
        const int et  = idx & 7;
        const int e0  = et << 4;
        const unsigned short* W = (out == 0) ? wqb : (out == 1) ? wkb : wvb;
        const float* bias = (out == 0) ? bq : (out == 1) ? bk : bv;
        const float scale = (out == 0) ? LOG2E : 1.0f;

        s16x8 af[8];
        const unsigned short* wp = W + (e0 + lx) * C_ + hi * 8;
#pragma unroll
        for (int ks = 0; ks < 8; ++ks) af[ks] = *(const s16x8*)(wp + ks * 32);

        float bi[4];
#pragma unroll
        for (int r = 0; r < 4; ++r) bi[r] = bias[e0 + hi * 4 + r];

#pragma unroll
        for (int nt = 0; nt < 4; ++nt) {
            f32x4 acc = {0.f, 0.f, 0.f, 0.f};
#pragma unroll
            for (int ks = 0; ks < 8; ++ks) {
                s16x8 xb = *(const s16x8*)&xs[(nt * 16 + lx) * 264 + ks * 32 + hi * 8];
                acc = __builtin_amdgcn_mfma_f32_16x16x32_bf16(af[ks], xb, acc, 0, 0, 0);
            }
            const int n = n0 + nt * 16 + lx;
            if (out < 2) {
                unsigned short* dst =
                    ((out == 0) ? Q : K) + ((size_t)(b * N_ + n) << 7) + e0 + hi * 4;
                s16x4 pk;
#pragma unroll
                for (int r = 0; r < 4; ++r) pk[r] = (short)f2bf((acc[r] + bi[r]) * scale);
                *(s16x4*)dst = pk;
            } else {
#pragma unroll
                for (int r = 0; r < 4; ++r)
                    Vt[((size_t)(b * E_ + e0 + hi * 4 + r) << 12) + n] =
                        f2bf(acc[r] + bi[r]);
            }
        }
    }
}

// ---------------------------------------------------------------------------
// Attention partial. 1024 blocks: b = blk&7 (XCD pin), idx = blk>>3:
// sl = idx>>5 (kv slice 0..3), qt = idx&31 (q-tile of 128).
// Wave w: q rows qt*128 + w*32. Double-buffered K/V, 1 barrier/iter.
// ---------------------------------------------------------------------------
__global__ __launch_bounds__(256, 2) void attn_partial(
    const unsigned short* __restrict__ Q, const unsigned short* __restrict__ K,
    const unsigned short* __restrict__ Vt,
    unsigned short* __restrict__ featP, float* __restrict__ denomP)
{
    __shared__ unsigned short Ks[2][64 * 128];   // [buf][kv][e-granule swz]
    __shared__ unsigned short Vs[2][128 * 64];   // [buf][e][kv-granule swz]
    __shared__ unsigned short Ps[4][32 * 64];    // per-wave [q][kv col swz]

    const int tid = threadIdx.x;
    const int b   = blockIdx.x & 7;
    const int idx = blockIdx.x >> 3;
    const int sl  = idx >> 5;      // kv slice 0..3
    const int qt  = idx & 31;      // q tile (128 rows)
    const int w = tid >> 6, l = tid & 63, hi = l >> 4, lx = l & 15;
    const int q0 = qt * 128 + w * 32;

    // hoisted Q fragments: 2 subtiles x 4 ks
    s16x8 qA[2][4];
#pragma unroll
    for (int qf = 0; qf < 2; ++qf) {
        const unsigned short* qp =
            Q + ((size_t)(b * N_ + q0 + qf * 16 + lx) << 7) + hi * 8;
#pragma unroll
        for (int ks = 0; ks < 4; ++ks) qA[qf][ks] = *(const s16x8*)(qp + ks * 32);
    }

    f32x4 feat[2][8];
#pragma unroll
    for (int qf = 0; qf < 2; ++qf)
#pragma unroll
        for (int ef = 0; ef < 8; ++ef) feat[qf][ef] = (f32x4){0.f, 0.f, 0.f, 0.f};
    float dAcc[8];
#pragma unroll
    for (int i = 0; i < 8; ++i) dAcc[i] = 0.f;

    const unsigned short* Kg = K + ((size_t)(b * N_) << 7);
    const unsigned short* Vg = Vt + ((size_t)(b * E_) << 12);
    unsigned short* pw = &Ps[w][0];

    // fixed per-thread staging geometry (flat = tid + i*256, 16B granules)
    //   K: row=flat>>4 (64 rows), src granule c16=flat&15; LDS granule c16^(row&7)
    //   V: e=flat>>3 (128 rows), src granule c8=flat&7;  LDS granule c8^(e&7)
    const int kRow[4] = { tid >> 4, (tid + 256) >> 4, (tid + 512) >> 4, (tid + 768) >> 4 };
    const int kC16 = tid & 15;
    const int vE[4]  = { tid >> 3, (tid + 256) >> 3, (tid + 512) >> 3, (tid + 768) >> 3 };
    const int vC8 = tid & 7;

    s16x8 nk[4], nv[4];
    // prologue: load + stage tile 0 into buf 0
    {
        const int kv0 = sl * SLICE_KV;
#pragma unroll
        for (int i = 0; i < 4; ++i)
            nk[i] = *(const s16x8*)(Kg + (size_t)(kv0 + kRow[i]) * 128 + kC16 * 8);
#pragma unroll
        for (int i = 0; i < 4; ++i)
            nv[i] = *(const s16x8*)(Vg + ((size_t)vE[i] << 12) + kv0 + vC8 * 8);
#pragma unroll
        for (int i = 0; i < 4; ++i)
            *(s16x8*)&Ks[0][kRow[i] * 128 + ((kC16 ^ (kRow[i] & 7)) << 3)] = nk[i];
#pragma unroll
        for (int i = 0; i < 4; ++i)
            *(s16x8*)&Vs[0][vE[i] * 64 + ((vC8 ^ (vE[i] & 7)) << 3)] = nv[i];
    }
    __syncthreads();

    for (int it = 0; it < NTILES; ++it) {
        const int cur = it & 1;
        const bool pf = (it + 1 < NTILES);
        // issue next-tile global loads early (hide L2 latency under compute)
        if (pf) {
            const int kvn = sl * SLICE_KV + (it + 1) * 64;
#pragma unroll
            for (int i = 0; i < 4; ++i)
                nk[i] = *(const s16x8*)(Kg + (size_t)(kvn + kRow[i]) * 128 + kC16 * 8);
#pragma unroll
            for (int i = 0; i < 4; ++i)
                nv[i] = *(const s16x8*)(Vg + ((size_t)vE[i] << 12) + kvn + vC8 * 8);
        }

        // QK^T + exp2 + P->LDS (per-wave slice; swizzled column)
        const unsigned short* kxb = &Ks[cur][0];
#pragma unroll
        for (int kvf = 0; kvf < 4; ++kvf) {
            s16x8 kb[4];
#pragma unroll
            for (int ks = 0; ks < 4; ++ks)
                kb[ks] = *(const s16x8*)&kxb[(kvf * 16 + lx) * 128 +
                                             (((ks * 4 + hi) ^ (lx & 7)) << 3)];
            f32x4 s0 = {0.f, 0.f, 0.f, 0.f}, s1 = {0.f, 0.f, 0.f, 0.f};
#pragma unroll
            for (int ks = 0; ks < 4; ++ks) {
                s0 = __builtin_amdgcn_mfma_f32_16x16x32_bf16(qA[0][ks], kb[ks], s0, 0, 0, 0);
                s1 = __builtin_amdgcn_mfma_f32_16x16x32_bf16(qA[1][ks], kb[ks], s1, 0, 0, 0);
            }
#pragma unroll
            for (int r = 0; r < 4; ++r) {
                const int key = ((hi * 4 + r) & 7) << 3;   // row&7 key (qf-indep)
                float p0 = __builtin_exp2f(s0[r] - SHIFT2);
                float p1 = __builtin_exp2f(s1[r] - SHIFT2);
                dAcc[r]     += p0;
                dAcc[4 + r] += p1;
                pw[(hi * 4 + r) * 64      + ((kvf * 16 + lx) ^ key)] = f2bf(p0);
                pw[(16 + hi * 4 + r) * 64 + ((kvf * 16 + lx) ^ key)] = f2bf(p1);
            }
        }
        // PV: feat[32q x 128e] += P @ V (P wave-private: no barrier)
        const unsigned short* vxb = &Vs[cur][0];
#pragma unroll
        for (int ks = 0; ks < 2; ++ks) {
            const int pkey = (lx & 7) << 3;
            s16x8 pa0 = *(const s16x8*)&pw[(lx)      * 64 + ((ks * 32 + hi * 8) ^ pkey)];
            s16x8 pa1 = *(const s16x8*)&pw[(16 + lx) * 64 + ((ks * 32 + hi * 8) ^ pkey)];
#pragma unroll
            for (int ef = 0; ef < 8; ++ef) {
                s16x8 vb = *(const s16x8*)&vxb[(ef * 16 + lx) * 64 +
                                               (((ks * 4 + hi) ^ (lx & 7)) << 3)];
                feat[0][ef] = __builtin_amdgcn_mfma_f32_16x16x32_bf16(pa0, vb, feat[0][ef], 0, 0, 0);
                feat[1][ef] = __builtin_amdgcn_mfma_f32_16x16x32_bf16(pa1, vb, feat[1][ef], 0, 0, 0);
            }
        }

        // write prefetched tile into the other buffer, then single barrier
        if (pf) {
            const int nxt = cur ^ 1;
#pragma unroll
            for (int i = 0; i < 4; ++i)
                *(s16x8*)&Ks[nxt][kRow[i] * 128 + ((kC16 ^ (kRow[i] & 7)) << 3)] = nk[i];
#pragma unroll
            for (int i = 0; i < 4; ++i)
                *(s16x8*)&Vs[nxt][vE[i] * 64 + ((vC8 ^ (vE[i] & 7)) << 3)] = nv[i];
            __syncthreads();
        }
    }

    // denom: reduce over kv lanes (lx)
#pragma unroll
    for (int i = 0; i < 8; ++i) {
        float v = dAcc[i];
        v += __shfl_xor(v, 1); v += __shfl_xor(v, 2);
        v += __shfl_xor(v, 4); v += __shfl_xor(v, 8);
        dAcc[i] = v;
    }
    const size_t qg = (size_t)((sl * 8 + b) * N_ + q0);
    if (lx == 0) {
        float* dP = denomP + qg;
#pragma unroll
        for (int qf = 0; qf < 2; ++qf)
#pragma unroll
            for (int r = 0; r < 4; ++r)
                dP[qf * 16 + hi * 4 + r] = dAcc[qf * 4 + r];
    }
    unsigned short* fP = featP + (qg << 7);
#pragma unroll
    for (int qf = 0; qf < 2; ++qf)
#pragma unroll
        for (int ef = 0; ef < 8; ++ef)
#pragma unroll
            for (int r = 0; r < 4; ++r)
                fP[(qf * 16 + hi * 4 + r) * 128 + ef * 16 + lx] =
                    f2bf(feat[qf][ef][r]);
}

// ---------------------------------------------------------------------------
// Combine: sum 4 kv-slice partials, normalize, out-proj (swapped operands ->
// n-coalesced stores; B-frags direct s16x8 from wob) + bias + residual.
// grid: 8 b x 64 n-tiles of 64.
// ---------------------------------------------------------------------------
__global__ __launch_bounds__(256, 2) void combine_kernel(
    const unsigned short* __restrict__ featP, const float* __restrict__ denomP,
    const unsigned short* __restrict__ wob, const float* __restrict__ bo,
    const float* __restrict__ x, float* __restrict__ out)
{
    __shared__ unsigned short fs[64 * 136];   // [q][e], stride 272B

    const int tid = threadIdx.x;
    const int b  = blockIdx.x & 7;
    const int nt = blockIdx.x >> 3;          // 0..63

    // sum partials + normalize -> fs (bf16)
    {
        const int q = tid >> 2, eb = (tid & 3) * 32;
        const int n = nt * 64 + q;
        float den = 0.f;
#pragma unroll
        for (int s = 0; s < SLICES; ++s)
            den += denomP[(size_t)((s * 8 + b) * N_) + n];
        const float inv = 1.f / den;
#pragma unroll
        for (int e8 = 0; e8 < 4; ++e8) {
            float acc[8];
#pragma unroll
            for (int j = 0; j < 8; ++j) acc[j] = 0.f;
#pragma unroll
            for (int s = 0; s < SLICES; ++s) {
                s16x8 v = *(const s16x8*)(featP +
                    (((size_t)((s * 8 + b) * N_) + n) << 7) + eb + e8 * 8);
#pragma unroll
                for (int j = 0; j < 8; ++j) acc[j] += bf2f((unsigned short)v[j]);
            }
            s16x8 o;
#pragma unroll
            for (int j = 0; j < 8; ++j) o[j] = (short)f2bf(acc[j] * inv);
            *(s16x8*)&fs[q * 136 + eb + e8 * 8] = o;
        }
    }
    __syncthreads();

    const int w = tid >> 6, l = tid & 63, hi = l >> 4, lx = l & 15;

    // B-frags of feat (col = q)
    s16x8 fa[4];
#pragma unroll
    for (int ks = 0; ks < 4; ++ks)
        fa[ks] = *(const s16x8*)&fs[(w * 16 + lx) * 136 + ks * 32 + hi * 8];

    const int n = nt * 64 + w * 16 + lx;
    const float* xb = x + ((size_t)(b * C_) << 12);
    float* ob = out + ((size_t)(b * C_) << 12);
#pragma unroll 1
    for (int ct = 0; ct < 16; ++ct) {
        const unsigned short* wp = wob + (ct * 16 + lx) * 128 + hi * 8;
        f32x4 acc = {0.f, 0.f, 0.f, 0.f};
#pragma unroll
        for (int ks = 0; ks < 4; ++ks) {
            s16x8 wb = *(const s16x8*)(wp + ks * 32);
            // swapped: D[row=c][col=n]
            acc = __builtin_amdgcn_mfma_f32_16x16x32_bf16(wb, fa[ks], acc, 0, 0, 0);
        }
#pragma unroll
        for (int r = 0; r < 4; ++r) {
            const int c = ct * 16 + hi * 4 + r;
            const size_t off = ((size_t)c << 12) + n;
            ob[off] = acc[r] + bo[c] + xb[off];
        }
    }
}

extern "C" void kernel_launch(void* const* d_in, const int* in_sizes, int n_in,
                              void* d_out, int out_size, void* d_ws, size_t ws_size,
                              hipStream_t stream) {
    (void)in_sizes; (void)n_in; (void)out_size; (void)ws_size;
    const float* x  = (const float*)d_in[0];
    const float* wq = (const float*)d_in[1];
    const float* bq = (const float*)d_in[2];
    const float* wk = (const float*)d_in[3];
    const float* bk = (const float*)d_in[4];
    const float* wv = (const float*)d_in[5];
    const float* bv = (const float*)d_in[6];
    const float* wo = (const float*)d_in[7];
    const float* bo = (const float*)d_in[8];

    unsigned short* Q  = (unsigned short*)d_ws;                 // [B,N,E] bf16 (pre-scaled by log2e)
    unsigned short* K  = Q + (size_t)B_ * N_ * E_;
    unsigned short* Vt = K + (size_t)B_ * N_ * E_;              // [B,E,N] bf16
    unsigned short* featP = Vt + (size_t)B_ * N_ * E_;          // [SLICES][B][N][E] bf16
    float* denomP = (float*)(featP + (size_t)SLICES * B_ * N_ * E_); // [SLICES][B][N]
    unsigned short* wqb = (unsigned short*)(denomP + (size_t)SLICES * B_ * N_);
    unsigned short* wkb = wqb + E_ * C_;
    unsigned short* wvb = wkb + E_ * C_;
    unsigned short* wob = wvb + E_ * C_;                        // [C,E] bf16

    convert_w<<<dim3(128), dim3(256), 0, stream>>>(
        wq, wk, wv, wo, wqb, wkb, wvb, wob);
    qkv_kernel<<<dim3(B_ * (N_ / 64)), dim3(256), 0, stream>>>(
        x, wqb, bq, wkb, bk, wvb, bv, Q, K, Vt);
    attn_partial<<<dim3(B_ * 32 * SLICES), dim3(256), 0, stream>>>(
        Q, K, Vt, featP, denomP);
    combine_kernel<<<dim3(B_ * 64), dim3(256), 0, stream>>>(
        featP, denomP, wob, bo, x, (float*)d_out);
}